// Round 10
// baseline (842.275 us; speedup 1.0000x reference)
//
#include <hip/hip_runtime.h>
#include <hip/hip_bf16.h>
#include <math.h>

// SlotAttention: B=64 N=4096 F=256 D=256 KVQ=256 H=4 S=8 DH=64 ITERS=3
// Round 10: r9 K/V-elimination kept; iteration tail (U-reduce + Wv + GRU +
// LN + q~) fused into ONE 512-thread kernel; k_att grid (8,64) -> 8 partials.

using frag_ab = __attribute__((ext_vector_type(8))) short;   // 8 bf16
using f32x4  = __attribute__((ext_vector_type(4))) float;

__device__ __forceinline__ unsigned short f2bf(float f) {
  unsigned int x = __float_as_uint(f);
  x += 0x7fffu + ((x >> 16) & 1u);   // RNE
  return (unsigned short)(x >> 16);
}
__device__ __forceinline__ float bf2f(unsigned short u) {
  return __uint_as_float((unsigned int)u << 16);
}

// ---------------------------------------------------------------------------
__global__ void k_transpose(const float* __restrict__ wih,
                            const float* __restrict__ whh,
                            const float* __restrict__ wv,
                            float* __restrict__ wihT, float* __restrict__ whhT,
                            float* __restrict__ wvT) {
  const int idx = blockIdx.x * 256 + threadIdx.x;
  if (idx < 768 * 256) {
    const int g = idx >> 8, k = idx & 255;
    wihT[k * 768 + g] = wih[idx];
  } else if (idx < 2 * 768 * 256) {
    const int j = idx - 768 * 256;
    const int g = j >> 8, k = j & 255;
    whhT[k * 768 + g] = whh[j];
  } else {
    const int j = idx - 2 * 768 * 256;
    const int c = j >> 8, k = j & 255;
    wvT[k * 256 + c] = wv[j];
  }
}

// ---------------------------------------------------------------------------
// M[h][D][f] = SCALE * sum_d wq[h*64+d][D] * wk[h*64+d][f]
__global__ __launch_bounds__(256) void k_mprep(const float* __restrict__ wq,
                                               const float* __restrict__ wk,
                                               float* __restrict__ M) {
  const int D = blockIdx.x, h = blockIdx.y, f = threadIdx.x;
  float acc = 0.f;
#pragma unroll 8
  for (int d = 0; d < 64; ++d)
    acc += wq[(h * 64 + d) * 256 + D] * wk[(h * 64 + d) * 256 + f];
  M[((h * 256) + D) * 256 + f] = acc * 0.125f;
}

// ---------------------------------------------------------------------------
// Pre-pass: dual-layout LN output. Block = 64 rows. Wave w does 16 rows.
__global__ __launch_bounds__(256) void k_precvt(
    const float* __restrict__ xsrc, const float* __restrict__ lnw,
    const float* __restrict__ lnb, unsigned short* __restrict__ Xh,
    unsigned short* __restrict__ XhT) {
  __shared__ __align__(16) unsigned short XT[256 * 68];  // row stride 136B
  const int t = threadIdx.x;
  const int lane = t & 63, w = t >> 6;
  const long row0 = (long)blockIdx.x * 64;
  const long b = row0 >> 12;
  const long j0 = row0 & 4095;

  float w4[4], b4[4];
#pragma unroll
  for (int k = 0; k < 4; ++k) {
    w4[k] = lnw[k * 64 + lane];
    b4[k] = lnb[k * 64 + lane];
  }
  for (int rr = 0; rr < 16; ++rr) {
    const long row = row0 + w * 16 + rr;
    float x[4];
    float s = 0.f, ss = 0.f;
#pragma unroll
    for (int k = 0; k < 4; ++k) {
      x[k] = xsrc[row * 256 + k * 64 + lane];
      s += x[k];
      ss += x[k] * x[k];
    }
#pragma unroll
    for (int m = 1; m < 64; m <<= 1) {
      s += __shfl_xor(s, m);
      ss += __shfl_xor(ss, m);
    }
    const float mean = s * (1.f / 256.f);
    const float rstd = rsqrtf(ss * (1.f / 256.f) - mean * mean + 1e-5f);
#pragma unroll
    for (int k = 0; k < 4; ++k) {
      const unsigned short u = f2bf((x[k] - mean) * rstd * w4[k] + b4[k]);
      Xh[row * 256 + k * 64 + lane] = u;
      *(unsigned short*)((char*)XT + (k * 64 + lane) * 136 + (w * 16 + rr) * 2) = u;
    }
  }
  __syncthreads();
#pragma unroll
  for (int fp = 0; fp < 4; ++fp) {
    const int f = fp * 64 + (t >> 2);
    const int jq = t & 3;
    uint2 v0 = *(const uint2*)((const char*)XT + f * 136 + jq * 32 + 0);
    uint2 v1 = *(const uint2*)((const char*)XT + f * 136 + jq * 32 + 8);
    uint2 v2 = *(const uint2*)((const char*)XT + f * 136 + jq * 32 + 16);
    uint2 v3 = *(const uint2*)((const char*)XT + f * 136 + jq * 32 + 24);
    unsigned short* dst = XhT + (b * 256 + f) * 4096 + j0 + jq * 16;
    *(uint4*)(dst) = make_uint4(v0.x, v0.y, v1.x, v1.y);
    *(uint4*)(dst + 8) = make_uint4(v2.x, v2.y, v3.x, v3.y);
  }
}

// ---------------------------------------------------------------------------
// svx[b][f] = sum_j xh[b][j][f]  (iteration-invariant)
__global__ __launch_bounds__(256) void k_sv(const unsigned short* __restrict__ XhT,
                                            float* __restrict__ svx) {
  const int b = blockIdx.x >> 2, fq = blockIdx.x & 3;
  const int lane = threadIdx.x & 63, w = threadIdx.x >> 6;
  for (int rr = 0; rr < 16; ++rr) {
    const int f = fq * 64 + w * 16 + rr;
    const unsigned short* p = XhT + ((long)(b * 256 + f)) * 4096;
    float s = 0.f;
#pragma unroll
    for (int i = 0; i < 8; ++i) {
      const uint4 v = *(const uint4*)(p + i * 512 + lane * 8);
      s += bf2f((unsigned short)(v.x & 0xffff)) + bf2f((unsigned short)(v.x >> 16)) +
           bf2f((unsigned short)(v.y & 0xffff)) + bf2f((unsigned short)(v.y >> 16)) +
           bf2f((unsigned short)(v.z & 0xffff)) + bf2f((unsigned short)(v.z >> 16)) +
           bf2f((unsigned short)(v.w & 0xffff)) + bf2f((unsigned short)(v.w >> 16));
    }
#pragma unroll
    for (int m = 1; m < 64; m <<= 1) s += __shfl_xor(s, m);
    if (lane == 0) svx[b * 256 + f] = s;
  }
}

// ---------------------------------------------------------------------------
// Initial q~ only: LN(slots) + q~[b][ih][f], bf16 pre-swizzled.
__global__ __launch_bounds__(256) void k_q(
    const float* __restrict__ slots, const float* __restrict__ lnw,
    const float* __restrict__ lnb, const float* __restrict__ M,
    unsigned short* __restrict__ qt) {
  __shared__ float sl[8 * 256];
  __shared__ float mstat[8], rstat[8];
  const int b = blockIdx.x, h = blockIdx.y, t = threadIdx.x;
#pragma unroll
  for (int i = 0; i < 8; ++i) sl[i * 256 + t] = slots[b * 2048 + i * 256 + t];
  __syncthreads();
  if (t < 8) {
    float s = 0.f, ss = 0.f;
    for (int k = 0; k < 256; ++k) {
      const float x = sl[t * 256 + k];
      s += x;
      ss += x * x;
    }
    const float m = s * (1.f / 256.f);
    mstat[t] = m;
    rstat[t] = rsqrtf(ss * (1.f / 256.f) - m * m + 1e-5f);
  }
  __syncthreads();
  const float w = lnw[t], bb = lnb[t];
#pragma unroll
  for (int i = 0; i < 8; ++i)
    sl[i * 256 + t] = (sl[i * 256 + t] - mstat[i]) * rstat[i] * w + bb;
  __syncthreads();
  float acc[8] = {};
  const float* Mh = M + h * 65536;
  for (int D = 0; D < 256; ++D) {
    const float m = Mh[D * 256 + t];
#pragma unroll
    for (int i = 0; i < 8; ++i) acc[i] += sl[i * 256 + D] * m;
  }
#pragma unroll
  for (int i = 0; i < 8; ++i) {
    const int ih = i * 4 + h;
    *(unsigned short*)((char*)qt + b * 16384 + ih * 512 +
                       ((2 * t) ^ ((ih & 7) << 4))) = f2bf(acc[i]);
  }
}

// ---------------------------------------------------------------------------
// Barrier-free attention core. Grid (8 jt, 64 b); wave owns 128 j (4 chunks).
template <bool LAST>
__global__ __launch_bounds__(256) void k_att(
    const unsigned short* __restrict__ qt, const unsigned short* __restrict__ Xh,
    const unsigned short* __restrict__ XhT, float* __restrict__ upart,
    float* __restrict__ rowsum_part, float* __restrict__ attn_out) {
  __shared__ __align__(16) unsigned short Qs[32 * 256];
  __shared__ __align__(16) unsigned short Ps[4][1024];
  __shared__ float ured[4][2048];
  __shared__ float wred[4][32];
  const int t = threadIdx.x;
  const int lane = t & 63, wid = t >> 6;
  const int li = lane & 15, kg = lane >> 4;
  const int b = blockIdx.y;
  const long j0 = (long)blockIdx.x * 512 + wid * 128;

#pragma unroll
  for (int rnd = 0; rnd < 4; ++rnd)
    __builtin_amdgcn_global_load_lds(
        (const unsigned int*)((const char*)qt + b * 16384 + rnd * 4096 + t * 16),
        (unsigned int*)((char*)Qs + rnd * 4096 + t * 16), 16, 0, 0);
  __syncthreads();

  float rsum0 = 0.f, rsum1 = 0.f;
  f32x4 pv[2][16];
#pragma unroll
  for (int s = 0; s < 2; ++s)
#pragma unroll
    for (int ft = 0; ft < 16; ++ft) pv[s][ft] = (f32x4){0.f, 0.f, 0.f, 0.f};

  unsigned short* Pw = Ps[wid];

  for (int ch = 0; ch < 4; ++ch) {
    const long jc = j0 + ch * 32;
    f32x4 dacc[2][2];
    dacc[0][0] = (f32x4){0.f, 0.f, 0.f, 0.f};
    dacc[0][1] = (f32x4){0.f, 0.f, 0.f, 0.f};
    dacc[1][0] = (f32x4){0.f, 0.f, 0.f, 0.f};
    dacc[1][1] = (f32x4){0.f, 0.f, 0.f, 0.f};
#pragma unroll
    for (int jsub = 0; jsub < 2; ++jsub) {
      frag_ab kf[8];
      const unsigned short* kp =
          Xh + ((long)b * 4096 + jc + jsub * 16 + li) * 256 + kg * 8;
#pragma unroll
      for (int ks = 0; ks < 8; ++ks) kf[ks] = *(const frag_ab*)(kp + ks * 32);
#pragma unroll
      for (int g = 0; g < 2; ++g) {
        const char* qrow = (const char*)Qs + (g * 16 + li) * 512;
        const int swz = (li & 7) << 4;
#pragma unroll
        for (int ks = 0; ks < 8; ++ks) {
          const frag_ab qf = *(const frag_ab*)(qrow + ((ks * 64 + kg * 16) ^ swz));
          dacc[jsub][g] = __builtin_amdgcn_mfma_f32_16x16x32_bf16(
              kf[ks], qf, dacc[jsub][g], 0, 0, 0);
        }
      }
    }
    float p[2][2][4];
#pragma unroll
    for (int jsub = 0; jsub < 2; ++jsub) {
#pragma unroll
      for (int r = 0; r < 4; ++r) {
        const float d0 = dacc[jsub][0][r];
        const float d1 = dacc[jsub][1][r];
        float mx = fmaxf(d0, d1);
        mx = fmaxf(mx, __shfl_xor(mx, 1));
        mx = fmaxf(mx, __shfl_xor(mx, 2));
        mx = fmaxf(mx, __shfl_xor(mx, 4));
        mx = fmaxf(mx, __shfl_xor(mx, 8));
        float e0 = __expf(d0 - mx), e1 = __expf(d1 - mx);
        float sm = e0 + e1;
        sm += __shfl_xor(sm, 1);
        sm += __shfl_xor(sm, 2);
        sm += __shfl_xor(sm, 4);
        sm += __shfl_xor(sm, 8);
        const float inv = 1.f / sm;
        e0 *= inv;
        e1 *= inv;
        p[jsub][0][r] = e0;
        p[jsub][1][r] = e1;
        rsum0 += e0;
        rsum1 += e1;
        if (LAST) {
          float s0 = e0 + __shfl_xor(e0, 1);
          s0 += __shfl_xor(s0, 2);
          float s1 = e1 + __shfl_xor(e1, 1);
          s1 += __shfl_xor(s1, 2);
          if ((li & 3) == 0) {
            const long jg = jc + jsub * 16 + kg * 4 + r;
            attn_out[((long)b * 8 + (li >> 2)) * 4096 + jg] = s0 * 0.25f;
            attn_out[((long)b * 8 + 4 + (li >> 2)) * 4096 + jg] = s1 * 0.25f;
          }
        }
      }
    }
    asm volatile("s_waitcnt lgkmcnt(0)" ::: "memory");
#pragma unroll
    for (int g = 0; g < 2; ++g) {
      const int ih = g * 16 + li;
      char* prow = (char*)Pw + ih * 64;
      const int swz = ((ih >> 2) & 3) << 4;
#pragma unroll
      for (int jsub = 0; jsub < 2; ++jsub)
#pragma unroll
        for (int rp = 0; rp < 2; ++rp) {
          const unsigned int pk =
              (unsigned)f2bf(p[jsub][g][2 * rp]) |
              ((unsigned)f2bf(p[jsub][g][2 * rp + 1]) << 16);
          const int jb = (jsub * 16 + kg * 4 + 2 * rp) * 2;
          *(unsigned int*)(prow + (jb ^ swz)) = pk;
        }
    }
    asm volatile("s_waitcnt lgkmcnt(0)" ::: "memory");
    const frag_ab pa0 = *(const frag_ab*)(
        (const char*)Pw + li * 64 + ((kg * 16) ^ (((li >> 2) & 3) << 4)));
    const frag_ab pa1 = *(const frag_ab*)(
        (const char*)Pw + (16 + li) * 64 +
        ((kg * 16) ^ ((((16 + li) >> 2) & 3) << 4)));
#pragma unroll
    for (int ft = 0; ft < 16; ++ft) {
      const frag_ab vf = *(const frag_ab*)(
          XhT + ((long)b * 256 + ft * 16 + li) * 4096 + jc + kg * 8);
      pv[0][ft] = __builtin_amdgcn_mfma_f32_16x16x32_bf16(pa0, vf, pv[0][ft], 0, 0, 0);
      pv[1][ft] = __builtin_amdgcn_mfma_f32_16x16x32_bf16(pa1, vf, pv[1][ft], 0, 0, 0);
    }
  }

  rsum0 += __shfl_xor(rsum0, 16);
  rsum0 += __shfl_xor(rsum0, 32);
  rsum1 += __shfl_xor(rsum1, 16);
  rsum1 += __shfl_xor(rsum1, 32);
  if (lane < 16) {
    wred[wid][lane] = rsum0;
    wred[wid][16 + lane] = rsum1;
  }

  const long pb = (long)blockIdx.x * 64 + b;
#pragma unroll
  for (int p4 = 0; p4 < 4; ++p4) {
    __syncthreads();
    if ((kg >> 1) == (p4 & 1)) {
#pragma unroll
      for (int ft = 0; ft < 16; ++ft)
#pragma unroll
        for (int r = 0; r < 4; ++r)
          ured[wid][((kg & 1) * 4 + r) * 256 + ft * 16 + li] = pv[p4 >> 1][ft][r];
    }
    __syncthreads();
#pragma unroll
    for (int o = 0; o < 8; ++o) {
      const int idx = o * 256 + t;
      upart[(pb * 32 + p4 * 8 + o) * 256 + t] =
          ured[0][idx] + ured[1][idx] + ured[2][idx] + ured[3][idx];
    }
  }
  if (t < 32)
    rowsum_part[pb * 32 + t] = wred[0][t] + wred[1][t] + wred[2][t] + wred[3][t];
}

// ---------------------------------------------------------------------------
// Fused tail: U-reduce+renorm -> Wv -> GRU gates -> combine -> LN -> q~.
// One block per b, 512 threads (8 waves). All reductions fixed-order.
template <bool LAST>
__global__ __launch_bounds__(512) void k_tail(
    const float* __restrict__ upart, const float* __restrict__ svx,
    const float* __restrict__ rowsum_part, const float* __restrict__ wvT,
    const float* __restrict__ wihT, const float* __restrict__ whhT,
    const float* __restrict__ bih, const float* __restrict__ bhh,
    const float* __restrict__ lnw, const float* __restrict__ lnb,
    const float* __restrict__ M, float* __restrict__ slots,
    unsigned short* __restrict__ qt, float* __restrict__ dout) {
  __shared__ float xu[32 * 256];    // 32KB: U rows, later sn rows (0..2047)
  __shared__ float xl[8 * 256];     // updates, later snl
  __shared__ float hl[8 * 256];
  __shared__ float gbuf[6 * 2048];  // 48KB: [gate*2 + {i,h}][8r][256d]
  __shared__ float rs[32];
  __shared__ float mst[8], rst[8];
  const int t = threadIdx.x;
  const int b = blockIdx.x;
  if (t < 32) {
    float s2 = 0.f;
#pragma unroll
    for (int p = 0; p < 8; ++p) s2 += rowsum_part[((long)(p * 64 + b)) * 32 + t];
    rs[t] = 1.f / (s2 + 4096.f * 1e-8f);
  }
#pragma unroll
  for (int o = 0; o < 4; ++o) {
    const int idx = o * 512 + t;
    hl[idx] = slots[b * 2048 + idx];
  }
  __syncthreads();
  // phase 1: U-reduce + EPS renorm (8192 cells, 16/thread, 8 partials each)
  const int f = t & 255;
  const float svf = svx[b * 256 + f] * 1e-8f;
#pragma unroll
  for (int c = 0; c < 16; ++c) {
    const int o = (t >> 8) * 16 + c;
    float pp = 0.f;
#pragma unroll
    for (int p = 0; p < 8; ++p)
      pp += upart[(((long)(p * 64 + b)) * 32 + o) * 256 + f];
    xu[o * 256 + f] = (pp + svf) * rs[o];
  }
  __syncthreads();
  // phase 2: Wv projection -> xl[i][gd]
  {
    const int gd = t & 255;
    const int h = gd >> 6;
    const int ib = (t >> 8) * 4;
    float a4[4] = {0.f, 0.f, 0.f, 0.f};
#pragma unroll 4
    for (int ff = 0; ff < 256; ++ff) {
      const float wv = wvT[ff * 256 + gd];
#pragma unroll
      for (int j = 0; j < 4; ++j) a4[j] += wv * xu[((ib + j) * 4 + h) * 256 + ff];
    }
#pragma unroll
    for (int j = 0; j < 4; ++j) xl[(ib + j) * 256 + gd] = a4[j];
  }
  __syncthreads();
  // phase 3: GRU gate matvecs (768 cols in 2 passes)
#pragma unroll
  for (int pass = 0; pass < 2; ++pass) {
    const int col = (pass == 0) ? t : 512 + (t & 255);
    if (pass == 0 || t < 256) {
      float ai[8] = {}, ah[8] = {};
#pragma unroll 2
      for (int k = 0; k < 256; k += 2) {
        const float wi0 = wihT[(k + 0) * 768 + col];
        const float wi1 = wihT[(k + 1) * 768 + col];
        const float wh0 = whhT[(k + 0) * 768 + col];
        const float wh1 = whhT[(k + 1) * 768 + col];
#pragma unroll
        for (int r = 0; r < 8; ++r) {
          const float2 x2 = *(const float2*)(xl + r * 256 + k);
          const float2 h2 = *(const float2*)(hl + r * 256 + k);
          ai[r] += x2.x * wi0 + x2.y * wi1;
          ah[r] += h2.x * wh0 + h2.y * wh1;
        }
      }
      const int gate = col >> 8, cc = col & 255;
      const float bi = bih[col], bh = bhh[col];
#pragma unroll
      for (int r = 0; r < 8; ++r) {
        gbuf[(gate * 2 + 0) * 2048 + r * 256 + cc] = ai[r] + bi;
        gbuf[(gate * 2 + 1) * 2048 + r * 256 + cc] = ah[r] + bh;
      }
    }
  }
  __syncthreads();
  // combine: hn = (1-z)*n + z*h_old; sn -> xu[0..2047]
#pragma unroll
  for (int j = 0; j < 4; ++j) {
    const int idx = j * 512 + t;
    const int r = idx >> 8, d = idx & 255;
    const float gir = gbuf[0 * 2048 + r * 256 + d], ghr = gbuf[1 * 2048 + r * 256 + d];
    const float giz = gbuf[2 * 2048 + r * 256 + d], ghz = gbuf[3 * 2048 + r * 256 + d];
    const float gin = gbuf[4 * 2048 + r * 256 + d], ghn = gbuf[5 * 2048 + r * 256 + d];
    const float rr = 1.f / (1.f + __expf(-(gir + ghr)));
    const float zz = 1.f / (1.f + __expf(-(giz + ghz)));
    const float nn = tanhf(gin + rr * ghn);
    const float hn = (1.f - zz) * nn + zz * hl[r * 256 + d];
    slots[b * 2048 + idx] = hn;
    if (LAST) dout[b * 2048 + idx] = hn;
    xu[idx] = hn;
  }
  if (LAST) return;
  __syncthreads();
  // LN stats: wave w handles row w
  {
    const int wv_ = t >> 6, lane = t & 63;
    float s = 0.f, ss = 0.f;
#pragma unroll
    for (int u = 0; u < 4; ++u) {
      const float x = xu[wv_ * 256 + u * 64 + lane];
      s += x;
      ss += x * x;
    }
#pragma unroll
    for (int m = 1; m < 64; m <<= 1) {
      s += __shfl_xor(s, m);
      ss += __shfl_xor(ss, m);
    }
    if (lane == 0) {
      const float mn = s * (1.f / 256.f);
      mst[wv_] = mn;
      rst[wv_] = rsqrtf(ss * (1.f / 256.f) - mn * mn + 1e-5f);
    }
  }
  __syncthreads();
#pragma unroll
  for (int j = 0; j < 4; ++j) {
    const int idx = j * 512 + t;
    const int r = idx >> 8, d = idx & 255;
    xl[idx] = (xu[idx] - mst[r]) * rst[r] * lnw[d] + lnb[d];
  }
  __syncthreads();
  // phase 4: q~[ih][f] = sum_D snl[i][D] * M[h][D][f]; swizzled bf16 write
  {
    const int fq = t & 255;
    const int half = t >> 8;
    float acc[16];
#pragma unroll
    for (int c = 0; c < 16; ++c) acc[c] = 0.f;
#pragma unroll 2
    for (int D = 0; D < 256; ++D) {
      float m4[4];
#pragma unroll
      for (int h = 0; h < 4; ++h) m4[h] = M[(h * 256 + D) * 256 + fq];
#pragma unroll
      for (int c = 0; c < 16; ++c) {
        const int ih = half * 16 + c;
        acc[c] += xl[(ih >> 2) * 256 + D] * m4[ih & 3];
      }
    }
#pragma unroll
    for (int c = 0; c < 16; ++c) {
      const int ih = half * 16 + c;
      *(unsigned short*)((char*)qt + b * 16384 + ih * 512 +
                         ((2 * fq) ^ ((ih & 7) << 4))) = f2bf(acc[c]);
    }
  }
}

// ---------------------------------------------------------------------------
extern "C" void kernel_launch(void* const* d_in, const int* in_sizes, int n_in,
                              void* d_out, int out_size, void* d_ws,
                              size_t ws_size, hipStream_t stream) {
  const float* xin = (const float*)d_in[0];
  const float* cond = (const float*)d_in[1];
  const float* lnin_w = (const float*)d_in[2];
  const float* lnin_b = (const float*)d_in[3];
  const float* lns_w = (const float*)d_in[4];
  const float* lns_b = (const float*)d_in[5];
  const float* wq = (const float*)d_in[6];
  const float* wk = (const float*)d_in[7];
  const float* wv = (const float*)d_in[8];
  const float* gwih = (const float*)d_in[9];
  const float* gwhh = (const float*)d_in[10];
  const float* gbih = (const float*)d_in[11];
  const float* gbhh = (const float*)d_in[12];
  float* out = (float*)d_out;

  char* ws = (char*)d_ws;
  unsigned short* Xh = (unsigned short*)ws;   ws += 262144l * 256 * 2;      // 128MB
  unsigned short* XhT = (unsigned short*)ws;  ws += 64l * 256 * 4096 * 2;   // 128MB
  float* M = (float*)ws;                      ws += 4l * 256 * 256 * 4;     // 1MB
  unsigned short* qt = (unsigned short*)ws;   ws += 64l * 32 * 256 * 2;     // 1MB
  float* upart = (float*)ws;                  ws += 8l * 64 * 32 * 256 * 4; // 16MB
  float* svx = (float*)ws;                    ws += 64l * 256 * 4;
  float* rowsum_part = (float*)ws;            ws += 8l * 64 * 32 * 4;
  float* slots = (float*)ws;                  ws += 512l * 256 * 4;
  float* wihT = (float*)ws;                   ws += 256l * 768 * 4;
  float* whhT = (float*)ws;                   ws += 256l * 768 * 4;
  float* wvT = (float*)ws;                    ws += 256l * 256 * 4;
  // total ~278 MB

  hipMemcpyAsync(slots, cond, 512 * 256 * 4, hipMemcpyDeviceToDevice, stream);
  k_transpose<<<1792, 256, 0, stream>>>(gwih, gwhh, wv, wihT, whhT, wvT);
  k_mprep<<<dim3(256, 4), 256, 0, stream>>>(wq, wk, M);
  k_precvt<<<4096, 256, 0, stream>>>(xin, lnin_w, lnin_b, Xh, XhT);
  k_sv<<<256, 256, 0, stream>>>(XhT, svx);
  k_q<<<dim3(64, 4), 256, 0, stream>>>(slots, lns_w, lns_b, M, qt);

  // iter 0
  k_att<false><<<dim3(8, 64), 256, 0, stream>>>(qt, Xh, XhT, upart,
                                                rowsum_part, out + 131072);
  k_tail<false><<<64, 512, 0, stream>>>(upart, svx, rowsum_part, wvT, wihT,
                                        whhT, gbih, gbhh, lns_w, lns_b, M,
                                        slots, qt, out);
  // iter 1
  k_att<false><<<dim3(8, 64), 256, 0, stream>>>(qt, Xh, XhT, upart,
                                                rowsum_part, out + 131072);
  k_tail<false><<<64, 512, 0, stream>>>(upart, svx, rowsum_part, wvT, wihT,
                                        whhT, gbih, gbhh, lns_w, lns_b, M,
                                        slots, qt, out);
  // iter 2
  k_att<true><<<dim3(8, 64), 256, 0, stream>>>(qt, Xh, XhT, upart,
                                               rowsum_part, out + 131072);
  k_tail<true><<<64, 512, 0, stream>>>(upart, svx, rowsum_part, wvT, wihT,
                                       whhT, gbih, gbhh, lns_w, lns_b, M,
                                       slots, qt, out);
}

// Round 11
// 812.878 us; speedup vs baseline: 1.0362x; 1.0362x over previous
//
#include <hip/hip_runtime.h>
#include <hip/hip_bf16.h>
#include <math.h>

// SlotAttention: B=64 N=4096 F=256 D=256 KVQ=256 H=4 S=8 DH=64 ITERS=3
// Round 11: r10 structure, but the iteration tail is re-parallelized by
// slot-row: grid (4,64), each block owns 2 GRU rows end-to-end
// (U-reduce -> renorm -> Wv -> gates(thread=d, r/z/n together) -> combine ->
// block-local LN -> q~). One launch per iter, no cross-block deps.

using frag_ab = __attribute__((ext_vector_type(8))) short;   // 8 bf16
using f32x4  = __attribute__((ext_vector_type(4))) float;

__device__ __forceinline__ unsigned short f2bf(float f) {
  unsigned int x = __float_as_uint(f);
  x += 0x7fffu + ((x >> 16) & 1u);   // RNE
  return (unsigned short)(x >> 16);
}
__device__ __forceinline__ float bf2f(unsigned short u) {
  return __uint_as_float((unsigned int)u << 16);
}

// ---------------------------------------------------------------------------
__global__ void k_transpose(const float* __restrict__ wih,
                            const float* __restrict__ whh,
                            const float* __restrict__ wv,
                            float* __restrict__ wihT, float* __restrict__ whhT,
                            float* __restrict__ wvT) {
  const int idx = blockIdx.x * 256 + threadIdx.x;
  if (idx < 768 * 256) {
    const int g = idx >> 8, k = idx & 255;
    wihT[k * 768 + g] = wih[idx];
  } else if (idx < 2 * 768 * 256) {
    const int j = idx - 768 * 256;
    const int g = j >> 8, k = j & 255;
    whhT[k * 768 + g] = whh[j];
  } else {
    const int j = idx - 2 * 768 * 256;
    const int c = j >> 8, k = j & 255;
    wvT[k * 256 + c] = wv[j];
  }
}

// ---------------------------------------------------------------------------
// M[h][D][f] = SCALE * sum_d wq[h*64+d][D] * wk[h*64+d][f]
__global__ __launch_bounds__(256) void k_mprep(const float* __restrict__ wq,
                                               const float* __restrict__ wk,
                                               float* __restrict__ M) {
  const int D = blockIdx.x, h = blockIdx.y, f = threadIdx.x;
  float acc = 0.f;
#pragma unroll 8
  for (int d = 0; d < 64; ++d)
    acc += wq[(h * 64 + d) * 256 + D] * wk[(h * 64 + d) * 256 + f];
  M[((h * 256) + D) * 256 + f] = acc * 0.125f;
}

// ---------------------------------------------------------------------------
// Pre-pass: dual-layout LN output. Block = 64 rows. Wave w does 16 rows.
__global__ __launch_bounds__(256) void k_precvt(
    const float* __restrict__ xsrc, const float* __restrict__ lnw,
    const float* __restrict__ lnb, unsigned short* __restrict__ Xh,
    unsigned short* __restrict__ XhT) {
  __shared__ __align__(16) unsigned short XT[256 * 68];  // row stride 136B
  const int t = threadIdx.x;
  const int lane = t & 63, w = t >> 6;
  const long row0 = (long)blockIdx.x * 64;
  const long b = row0 >> 12;
  const long j0 = row0 & 4095;

  float w4[4], b4[4];
#pragma unroll
  for (int k = 0; k < 4; ++k) {
    w4[k] = lnw[k * 64 + lane];
    b4[k] = lnb[k * 64 + lane];
  }
  for (int rr = 0; rr < 16; ++rr) {
    const long row = row0 + w * 16 + rr;
    float x[4];
    float s = 0.f, ss = 0.f;
#pragma unroll
    for (int k = 0; k < 4; ++k) {
      x[k] = xsrc[row * 256 + k * 64 + lane];
      s += x[k];
      ss += x[k] * x[k];
    }
#pragma unroll
    for (int m = 1; m < 64; m <<= 1) {
      s += __shfl_xor(s, m);
      ss += __shfl_xor(ss, m);
    }
    const float mean = s * (1.f / 256.f);
    const float rstd = rsqrtf(ss * (1.f / 256.f) - mean * mean + 1e-5f);
#pragma unroll
    for (int k = 0; k < 4; ++k) {
      const unsigned short u = f2bf((x[k] - mean) * rstd * w4[k] + b4[k]);
      Xh[row * 256 + k * 64 + lane] = u;
      *(unsigned short*)((char*)XT + (k * 64 + lane) * 136 + (w * 16 + rr) * 2) = u;
    }
  }
  __syncthreads();
#pragma unroll
  for (int fp = 0; fp < 4; ++fp) {
    const int f = fp * 64 + (t >> 2);
    const int jq = t & 3;
    uint2 v0 = *(const uint2*)((const char*)XT + f * 136 + jq * 32 + 0);
    uint2 v1 = *(const uint2*)((const char*)XT + f * 136 + jq * 32 + 8);
    uint2 v2 = *(const uint2*)((const char*)XT + f * 136 + jq * 32 + 16);
    uint2 v3 = *(const uint2*)((const char*)XT + f * 136 + jq * 32 + 24);
    unsigned short* dst = XhT + (b * 256 + f) * 4096 + j0 + jq * 16;
    *(uint4*)(dst) = make_uint4(v0.x, v0.y, v1.x, v1.y);
    *(uint4*)(dst + 8) = make_uint4(v2.x, v2.y, v3.x, v3.y);
  }
}

// ---------------------------------------------------------------------------
// svx[b][f] = sum_j xh[b][j][f]  (iteration-invariant)
__global__ __launch_bounds__(256) void k_sv(const unsigned short* __restrict__ XhT,
                                            float* __restrict__ svx) {
  const int b = blockIdx.x >> 2, fq = blockIdx.x & 3;
  const int lane = threadIdx.x & 63, w = threadIdx.x >> 6;
  for (int rr = 0; rr < 16; ++rr) {
    const int f = fq * 64 + w * 16 + rr;
    const unsigned short* p = XhT + ((long)(b * 256 + f)) * 4096;
    float s = 0.f;
#pragma unroll
    for (int i = 0; i < 8; ++i) {
      const uint4 v = *(const uint4*)(p + i * 512 + lane * 8);
      s += bf2f((unsigned short)(v.x & 0xffff)) + bf2f((unsigned short)(v.x >> 16)) +
           bf2f((unsigned short)(v.y & 0xffff)) + bf2f((unsigned short)(v.y >> 16)) +
           bf2f((unsigned short)(v.z & 0xffff)) + bf2f((unsigned short)(v.z >> 16)) +
           bf2f((unsigned short)(v.w & 0xffff)) + bf2f((unsigned short)(v.w >> 16));
    }
#pragma unroll
    for (int m = 1; m < 64; m <<= 1) s += __shfl_xor(s, m);
    if (lane == 0) svx[b * 256 + f] = s;
  }
}

// ---------------------------------------------------------------------------
// Initial q~ only: LN(slots) + q~[b][ih][f], bf16 pre-swizzled.
__global__ __launch_bounds__(256) void k_q(
    const float* __restrict__ slots, const float* __restrict__ lnw,
    const float* __restrict__ lnb, const float* __restrict__ M,
    unsigned short* __restrict__ qt) {
  __shared__ float sl[8 * 256];
  __shared__ float mstat[8], rstat[8];
  const int b = blockIdx.x, h = blockIdx.y, t = threadIdx.x;
#pragma unroll
  for (int i = 0; i < 8; ++i) sl[i * 256 + t] = slots[b * 2048 + i * 256 + t];
  __syncthreads();
  if (t < 8) {
    float s = 0.f, ss = 0.f;
    for (int k = 0; k < 256; ++k) {
      const float x = sl[t * 256 + k];
      s += x;
      ss += x * x;
    }
    const float m = s * (1.f / 256.f);
    mstat[t] = m;
    rstat[t] = rsqrtf(ss * (1.f / 256.f) - m * m + 1e-5f);
  }
  __syncthreads();
  const float w = lnw[t], bb = lnb[t];
#pragma unroll
  for (int i = 0; i < 8; ++i)
    sl[i * 256 + t] = (sl[i * 256 + t] - mstat[i]) * rstat[i] * w + bb;
  __syncthreads();
  float acc[8] = {};
  const float* Mh = M + h * 65536;
  for (int D = 0; D < 256; ++D) {
    const float m = Mh[D * 256 + t];
#pragma unroll
    for (int i = 0; i < 8; ++i) acc[i] += sl[i * 256 + D] * m;
  }
#pragma unroll
  for (int i = 0; i < 8; ++i) {
    const int ih = i * 4 + h;
    *(unsigned short*)((char*)qt + b * 16384 + ih * 512 +
                       ((2 * t) ^ ((ih & 7) << 4))) = f2bf(acc[i]);
  }
}

// ---------------------------------------------------------------------------
// Barrier-free attention core (r10, unchanged). Grid (8 jt, 64 b).
template <bool LAST>
__global__ __launch_bounds__(256) void k_att(
    const unsigned short* __restrict__ qt, const unsigned short* __restrict__ Xh,
    const unsigned short* __restrict__ XhT, float* __restrict__ upart,
    float* __restrict__ rowsum_part, float* __restrict__ attn_out) {
  __shared__ __align__(16) unsigned short Qs[32 * 256];
  __shared__ __align__(16) unsigned short Ps[4][1024];
  __shared__ float ured[4][2048];
  __shared__ float wred[4][32];
  const int t = threadIdx.x;
  const int lane = t & 63, wid = t >> 6;
  const int li = lane & 15, kg = lane >> 4;
  const int b = blockIdx.y;
  const long j0 = (long)blockIdx.x * 512 + wid * 128;

#pragma unroll
  for (int rnd = 0; rnd < 4; ++rnd)
    __builtin_amdgcn_global_load_lds(
        (const unsigned int*)((const char*)qt + b * 16384 + rnd * 4096 + t * 16),
        (unsigned int*)((char*)Qs + rnd * 4096 + t * 16), 16, 0, 0);
  __syncthreads();

  float rsum0 = 0.f, rsum1 = 0.f;
  f32x4 pv[2][16];
#pragma unroll
  for (int s = 0; s < 2; ++s)
#pragma unroll
    for (int ft = 0; ft < 16; ++ft) pv[s][ft] = (f32x4){0.f, 0.f, 0.f, 0.f};

  unsigned short* Pw = Ps[wid];

  for (int ch = 0; ch < 4; ++ch) {
    const long jc = j0 + ch * 32;
    f32x4 dacc[2][2];
    dacc[0][0] = (f32x4){0.f, 0.f, 0.f, 0.f};
    dacc[0][1] = (f32x4){0.f, 0.f, 0.f, 0.f};
    dacc[1][0] = (f32x4){0.f, 0.f, 0.f, 0.f};
    dacc[1][1] = (f32x4){0.f, 0.f, 0.f, 0.f};
#pragma unroll
    for (int jsub = 0; jsub < 2; ++jsub) {
      frag_ab kf[8];
      const unsigned short* kp =
          Xh + ((long)b * 4096 + jc + jsub * 16 + li) * 256 + kg * 8;
#pragma unroll
      for (int ks = 0; ks < 8; ++ks) kf[ks] = *(const frag_ab*)(kp + ks * 32);
#pragma unroll
      for (int g = 0; g < 2; ++g) {
        const char* qrow = (const char*)Qs + (g * 16 + li) * 512;
        const int swz = (li & 7) << 4;
#pragma unroll
        for (int ks = 0; ks < 8; ++ks) {
          const frag_ab qf = *(const frag_ab*)(qrow + ((ks * 64 + kg * 16) ^ swz));
          dacc[jsub][g] = __builtin_amdgcn_mfma_f32_16x16x32_bf16(
              kf[ks], qf, dacc[jsub][g], 0, 0, 0);
        }
      }
    }
    float p[2][2][4];
#pragma unroll
    for (int jsub = 0; jsub < 2; ++jsub) {
#pragma unroll
      for (int r = 0; r < 4; ++r) {
        const float d0 = dacc[jsub][0][r];
        const float d1 = dacc[jsub][1][r];
        float mx = fmaxf(d0, d1);
        mx = fmaxf(mx, __shfl_xor(mx, 1));
        mx = fmaxf(mx, __shfl_xor(mx, 2));
        mx = fmaxf(mx, __shfl_xor(mx, 4));
        mx = fmaxf(mx, __shfl_xor(mx, 8));
        float e0 = __expf(d0 - mx), e1 = __expf(d1 - mx);
        float sm = e0 + e1;
        sm += __shfl_xor(sm, 1);
        sm += __shfl_xor(sm, 2);
        sm += __shfl_xor(sm, 4);
        sm += __shfl_xor(sm, 8);
        const float inv = 1.f / sm;
        e0 *= inv;
        e1 *= inv;
        p[jsub][0][r] = e0;
        p[jsub][1][r] = e1;
        rsum0 += e0;
        rsum1 += e1;
        if (LAST) {
          float s0 = e0 + __shfl_xor(e0, 1);
          s0 += __shfl_xor(s0, 2);
          float s1 = e1 + __shfl_xor(e1, 1);
          s1 += __shfl_xor(s1, 2);
          if ((li & 3) == 0) {
            const long jg = jc + jsub * 16 + kg * 4 + r;
            attn_out[((long)b * 8 + (li >> 2)) * 4096 + jg] = s0 * 0.25f;
            attn_out[((long)b * 8 + 4 + (li >> 2)) * 4096 + jg] = s1 * 0.25f;
          }
        }
      }
    }
    asm volatile("s_waitcnt lgkmcnt(0)" ::: "memory");
#pragma unroll
    for (int g = 0; g < 2; ++g) {
      const int ih = g * 16 + li;
      char* prow = (char*)Pw + ih * 64;
      const int swz = ((ih >> 2) & 3) << 4;
#pragma unroll
      for (int jsub = 0; jsub < 2; ++jsub)
#pragma unroll
        for (int rp = 0; rp < 2; ++rp) {
          const unsigned int pk =
              (unsigned)f2bf(p[jsub][g][2 * rp]) |
              ((unsigned)f2bf(p[jsub][g][2 * rp + 1]) << 16);
          const int jb = (jsub * 16 + kg * 4 + 2 * rp) * 2;
          *(unsigned int*)(prow + (jb ^ swz)) = pk;
        }
    }
    asm volatile("s_waitcnt lgkmcnt(0)" ::: "memory");
    const frag_ab pa0 = *(const frag_ab*)(
        (const char*)Pw + li * 64 + ((kg * 16) ^ (((li >> 2) & 3) << 4)));
    const frag_ab pa1 = *(const frag_ab*)(
        (const char*)Pw + (16 + li) * 64 +
        ((kg * 16) ^ ((((16 + li) >> 2) & 3) << 4)));
#pragma unroll
    for (int ft = 0; ft < 16; ++ft) {
      const frag_ab vf = *(const frag_ab*)(
          XhT + ((long)b * 256 + ft * 16 + li) * 4096 + jc + kg * 8);
      pv[0][ft] = __builtin_amdgcn_mfma_f32_16x16x32_bf16(pa0, vf, pv[0][ft], 0, 0, 0);
      pv[1][ft] = __builtin_amdgcn_mfma_f32_16x16x32_bf16(pa1, vf, pv[1][ft], 0, 0, 0);
    }
  }

  rsum0 += __shfl_xor(rsum0, 16);
  rsum0 += __shfl_xor(rsum0, 32);
  rsum1 += __shfl_xor(rsum1, 16);
  rsum1 += __shfl_xor(rsum1, 32);
  if (lane < 16) {
    wred[wid][lane] = rsum0;
    wred[wid][16 + lane] = rsum1;
  }

  const long pb = (long)blockIdx.x * 64 + b;
#pragma unroll
  for (int p4 = 0; p4 < 4; ++p4) {
    __syncthreads();
    if ((kg >> 1) == (p4 & 1)) {
#pragma unroll
      for (int ft = 0; ft < 16; ++ft)
#pragma unroll
        for (int r = 0; r < 4; ++r)
          ured[wid][((kg & 1) * 4 + r) * 256 + ft * 16 + li] = pv[p4 >> 1][ft][r];
    }
    __syncthreads();
#pragma unroll
    for (int o = 0; o < 8; ++o) {
      const int idx = o * 256 + t;
      upart[(pb * 32 + p4 * 8 + o) * 256 + t] =
          ured[0][idx] + ured[1][idx] + ured[2][idx] + ured[3][idx];
    }
  }
  if (t < 32)
    rowsum_part[pb * 32 + t] = wred[0][t] + wred[1][t] + wred[2][t] + wred[3][t];
}

// ---------------------------------------------------------------------------
// Row-split fused tail: grid (4 io, 64 b), 256 threads. Block owns slot rows
// i0=2io, i1=2io+1: U-reduce+renorm -> Wv -> gates (thread=d, r/z/n fused) ->
// combine -> block-local LN -> q~ chunk. One launch per iteration.
template <bool LAST>
__global__ __launch_bounds__(256) void k_tail(
    const float* __restrict__ upart, const float* __restrict__ svx,
    const float* __restrict__ rowsum_part, const float* __restrict__ wvT,
    const float* __restrict__ wihT, const float* __restrict__ whhT,
    const float* __restrict__ bih, const float* __restrict__ bhh,
    const float* __restrict__ lnw, const float* __restrict__ lnb,
    const float* __restrict__ M, float* __restrict__ slots,
    unsigned short* __restrict__ qt, float* __restrict__ dout) {
  __shared__ float xti[8][256];   // X~ rows ih = io*8 .. io*8+7
  __shared__ float upd[2][256];   // updates rows i0,i1; later snl rows
  __shared__ float hl[2][256];
  __shared__ float sn[2][256];
  __shared__ float rsl[8];
  __shared__ float mst[2], rst[2];
  const int t = threadIdx.x;
  const int io = blockIdx.x;
  const int b = blockIdx.y;
  const int i0 = io * 2, i1 = io * 2 + 1;

  if (t < 8) {
    float s2 = 0.f;
#pragma unroll
    for (int p = 0; p < 8; ++p)
      s2 += rowsum_part[((long)(p * 64 + b)) * 32 + io * 8 + t];
    rsl[t] = 1.f / (s2 + 4096.f * 1e-8f);
  }
  hl[0][t] = slots[b * 2048 + i0 * 256 + t];
  hl[1][t] = slots[b * 2048 + i1 * 256 + t];
  __syncthreads();
  // U-reduce + EPS renorm (rows ih = io*8+o, f = t)
  const float svf = svx[b * 256 + t] * 1e-8f;
#pragma unroll
  for (int o = 0; o < 8; ++o) {
    const int ih = io * 8 + o;
    float pp = 0.f;
#pragma unroll
    for (int p = 0; p < 8; ++p)
      pp += upart[(((long)(p * 64 + b)) * 32 + ih) * 256 + t];
    xti[o][t] = (pp + svf) * rsl[o];
  }
  __syncthreads();
  // Wv projection: d = t, h = t>>6 (wave-uniform); local rows o = h, 4+h
  {
    const int h = t >> 6;
    float a0 = 0.f, a1 = 0.f;
#pragma unroll 4
    for (int f = 0; f < 256; ++f) {
      const float wv = wvT[f * 256 + t];
      a0 += wv * xti[h][f];
      a1 += wv * xti[4 + h][f];
    }
    upd[0][t] = a0;
    upd[1][t] = a1;
  }
  __syncthreads();
  // gates + combine at d = t (cols t, 256+t, 512+t of the 768)
  float hn0, hn1;
  {
    float gir0 = 0, giz0 = 0, gin0 = 0, ghr0 = 0, ghz0 = 0, ghn0 = 0;
    float gir1 = 0, giz1 = 0, gin1 = 0, ghr1 = 0, ghz1 = 0, ghn1 = 0;
#pragma unroll 2
    for (int k = 0; k < 256; ++k) {
      const float wr = wihT[k * 768 + t];
      const float wz = wihT[k * 768 + 256 + t];
      const float wn = wihT[k * 768 + 512 + t];
      const float vr = whhT[k * 768 + t];
      const float vz = whhT[k * 768 + 256 + t];
      const float vn = whhT[k * 768 + 512 + t];
      const float x0 = upd[0][k], x1 = upd[1][k];
      const float h0 = hl[0][k], h1 = hl[1][k];
      gir0 += x0 * wr; giz0 += x0 * wz; gin0 += x0 * wn;
      ghr0 += h0 * vr; ghz0 += h0 * vz; ghn0 += h0 * vn;
      gir1 += x1 * wr; giz1 += x1 * wz; gin1 += x1 * wn;
      ghr1 += h1 * vr; ghz1 += h1 * vz; ghn1 += h1 * vn;
    }
    const float br = bih[t], bz = bih[256 + t], bn = bih[512 + t];
    const float cr = bhh[t], cz = bhh[256 + t], cn = bhh[512 + t];
    const float r0 = 1.f / (1.f + __expf(-(gir0 + br + ghr0 + cr)));
    const float z0 = 1.f / (1.f + __expf(-(giz0 + bz + ghz0 + cz)));
    const float n0 = tanhf(gin0 + bn + r0 * (ghn0 + cn));
    hn0 = (1.f - z0) * n0 + z0 * hl[0][t];
    const float r1 = 1.f / (1.f + __expf(-(gir1 + br + ghr1 + cr)));
    const float z1 = 1.f / (1.f + __expf(-(giz1 + bz + ghz1 + cz)));
    const float n1 = tanhf(gin1 + bn + r1 * (ghn1 + cn));
    hn1 = (1.f - z1) * n1 + z1 * hl[1][t];
  }
  slots[b * 2048 + i0 * 256 + t] = hn0;
  slots[b * 2048 + i1 * 256 + t] = hn1;
  if (LAST) {
    dout[b * 2048 + i0 * 256 + t] = hn0;
    dout[b * 2048 + i1 * 256 + t] = hn1;
    return;
  }
  sn[0][t] = hn0;
  sn[1][t] = hn1;
  __syncthreads();
  // block-local LN stats: wave 0 -> row 0, wave 1 -> row 1
  {
    const int wv_ = t >> 6, lane = t & 63;
    if (wv_ < 2) {
      float s = 0.f, ss = 0.f;
#pragma unroll
      for (int u = 0; u < 4; ++u) {
        const float x = sn[wv_][u * 64 + lane];
        s += x;
        ss += x * x;
      }
#pragma unroll
      for (int m = 1; m < 64; m <<= 1) {
        s += __shfl_xor(s, m);
        ss += __shfl_xor(ss, m);
      }
      if (lane == 0) {
        const float mn = s * (1.f / 256.f);
        mst[wv_] = mn;
        rst[wv_] = rsqrtf(ss * (1.f / 256.f) - mn * mn + 1e-5f);
      }
    }
  }
  __syncthreads();
  upd[0][t] = (sn[0][t] - mst[0]) * rst[0] * lnw[t] + lnb[t];  // snl rows
  upd[1][t] = (sn[1][t] - mst[1]) * rst[1] * lnw[t] + lnb[t];
  __syncthreads();
  // q~: rows ih = i*4+h for i in {i0,i1}; f = t; K = 256 D
  {
    float acc[8];
#pragma unroll
    for (int c = 0; c < 8; ++c) acc[c] = 0.f;
#pragma unroll 2
    for (int D = 0; D < 256; ++D) {
      const float s0 = upd[0][D], s1 = upd[1][D];
#pragma unroll
      for (int h = 0; h < 4; ++h) {
        const float m = M[(h * 256 + D) * 256 + t];
        acc[h] += s0 * m;
        acc[4 + h] += s1 * m;
      }
    }
#pragma unroll
    for (int c = 0; c < 8; ++c) {
      const int i = (c < 4) ? i0 : i1;
      const int h = c & 3;
      const int ih = i * 4 + h;
      *(unsigned short*)((char*)qt + b * 16384 + ih * 512 +
                         ((2 * t) ^ ((ih & 7) << 4))) = f2bf(acc[c]);
    }
  }
}

// ---------------------------------------------------------------------------
extern "C" void kernel_launch(void* const* d_in, const int* in_sizes, int n_in,
                              void* d_out, int out_size, void* d_ws,
                              size_t ws_size, hipStream_t stream) {
  const float* xin = (const float*)d_in[0];
  const float* cond = (const float*)d_in[1];
  const float* lnin_w = (const float*)d_in[2];
  const float* lnin_b = (const float*)d_in[3];
  const float* lns_w = (const float*)d_in[4];
  const float* lns_b = (const float*)d_in[5];
  const float* wq = (const float*)d_in[6];
  const float* wk = (const float*)d_in[7];
  const float* wv = (const float*)d_in[8];
  const float* gwih = (const float*)d_in[9];
  const float* gwhh = (const float*)d_in[10];
  const float* gbih = (const float*)d_in[11];
  const float* gbhh = (const float*)d_in[12];
  float* out = (float*)d_out;

  char* ws = (char*)d_ws;
  unsigned short* Xh = (unsigned short*)ws;   ws += 262144l * 256 * 2;      // 128MB
  unsigned short* XhT = (unsigned short*)ws;  ws += 64l * 256 * 4096 * 2;   // 128MB
  float* M = (float*)ws;                      ws += 4l * 256 * 256 * 4;     // 1MB
  unsigned short* qt = (unsigned short*)ws;   ws += 64l * 32 * 256 * 2;     // 1MB
  float* upart = (float*)ws;                  ws += 8l * 64 * 32 * 256 * 4; // 16MB
  float* svx = (float*)ws;                    ws += 64l * 256 * 4;
  float* rowsum_part = (float*)ws;            ws += 8l * 64 * 32 * 4;
  float* slots = (float*)ws;                  ws += 512l * 256 * 4;
  float* wihT = (float*)ws;                   ws += 256l * 768 * 4;
  float* whhT = (float*)ws;                   ws += 256l * 768 * 4;
  float* wvT = (float*)ws;                    ws += 256l * 256 * 4;
  // total ~278 MB

  hipMemcpyAsync(slots, cond, 512 * 256 * 4, hipMemcpyDeviceToDevice, stream);
  k_transpose<<<1792, 256, 0, stream>>>(gwih, gwhh, wv, wihT, whhT, wvT);
  k_mprep<<<dim3(256, 4), 256, 0, stream>>>(wq, wk, M);
  k_precvt<<<4096, 256, 0, stream>>>(xin, lnin_w, lnin_b, Xh, XhT);
  k_sv<<<256, 256, 0, stream>>>(XhT, svx);
  k_q<<<dim3(64, 4), 256, 0, stream>>>(slots, lns_w, lns_b, M, qt);

  // iter 0
  k_att<false><<<dim3(8, 64), 256, 0, stream>>>(qt, Xh, XhT, upart,
                                                rowsum_part, out + 131072);
  k_tail<false><<<dim3(4, 64), 256, 0, stream>>>(
      upart, svx, rowsum_part, wvT, wihT, whhT, gbih, gbhh, lns_w, lns_b, M,
      slots, qt, out);
  // iter 1
  k_att<false><<<dim3(8, 64), 256, 0, stream>>>(qt, Xh, XhT, upart,
                                                rowsum_part, out + 131072);
  k_tail<false><<<dim3(4, 64), 256, 0, stream>>>(
      upart, svx, rowsum_part, wvT, wihT, whhT, gbih, gbhh, lns_w, lns_b, M,
      slots, qt, out);
  // iter 2
  k_att<true><<<dim3(8, 64), 256, 0, stream>>>(qt, Xh, XhT, upart,
                                               rowsum_part, out + 131072);
  k_tail<true><<<dim3(4, 64), 256, 0, stream>>>(
      upart, svx, rowsum_part, wvT, wihT, whhT, gbih, gbhh, lns_w, lns_b, M,
      slots, qt, out);
}

// Round 12
// 803.278 us; speedup vs baseline: 1.0485x; 1.0120x over previous
//
#include <hip/hip_runtime.h>
#include <hip/hip_bf16.h>
#include <math.h>

// SlotAttention: B=64 N=4096 F=256 D=256 KVQ=256 H=4 S=8 DH=64 ITERS=3
// Round 12: r11, but all tail matvecs use per-thread CONTIGUOUS row streams
// (float4) from the ORIGINAL weight layouts (wih/whh/wv; M stored transposed
// as MT[h][f][D]) + LDS-broadcast activations. k_transpose dropped.

using frag_ab = __attribute__((ext_vector_type(8))) short;   // 8 bf16
using f32x4  = __attribute__((ext_vector_type(4))) float;

__device__ __forceinline__ unsigned short f2bf(float f) {
  unsigned int x = __float_as_uint(f);
  x += 0x7fffu + ((x >> 16) & 1u);   // RNE
  return (unsigned short)(x >> 16);
}
__device__ __forceinline__ float bf2f(unsigned short u) {
  return __uint_as_float((unsigned int)u << 16);
}
__device__ __forceinline__ float dot4(const float4 a, const float4 b) {
  return a.x * b.x + a.y * b.y + a.z * b.z + a.w * b.w;
}

// ---------------------------------------------------------------------------
// MT[h][f][D] = SCALE * sum_d wq[h*64+d][D] * wk[h*64+d][f]  (D contiguous)
__global__ __launch_bounds__(256) void k_mprep(const float* __restrict__ wq,
                                               const float* __restrict__ wk,
                                               float* __restrict__ MT) {
  const int f = blockIdx.x, h = blockIdx.y, D = threadIdx.x;
  float acc = 0.f;
#pragma unroll 8
  for (int d = 0; d < 64; ++d)
    acc += wq[(h * 64 + d) * 256 + D] * wk[(h * 64 + d) * 256 + f];
  MT[((long)(h * 256 + f)) * 256 + D] = acc * 0.125f;
}

// ---------------------------------------------------------------------------
// Pre-pass: dual-layout LN output. Block = 64 rows. Wave w does 16 rows.
__global__ __launch_bounds__(256) void k_precvt(
    const float* __restrict__ xsrc, const float* __restrict__ lnw,
    const float* __restrict__ lnb, unsigned short* __restrict__ Xh,
    unsigned short* __restrict__ XhT) {
  __shared__ __align__(16) unsigned short XT[256 * 68];  // row stride 136B
  const int t = threadIdx.x;
  const int lane = t & 63, w = t >> 6;
  const long row0 = (long)blockIdx.x * 64;
  const long b = row0 >> 12;
  const long j0 = row0 & 4095;

  float w4[4], b4[4];
#pragma unroll
  for (int k = 0; k < 4; ++k) {
    w4[k] = lnw[k * 64 + lane];
    b4[k] = lnb[k * 64 + lane];
  }
  for (int rr = 0; rr < 16; ++rr) {
    const long row = row0 + w * 16 + rr;
    float x[4];
    float s = 0.f, ss = 0.f;
#pragma unroll
    for (int k = 0; k < 4; ++k) {
      x[k] = xsrc[row * 256 + k * 64 + lane];
      s += x[k];
      ss += x[k] * x[k];
    }
#pragma unroll
    for (int m = 1; m < 64; m <<= 1) {
      s += __shfl_xor(s, m);
      ss += __shfl_xor(ss, m);
    }
    const float mean = s * (1.f / 256.f);
    const float rstd = rsqrtf(ss * (1.f / 256.f) - mean * mean + 1e-5f);
#pragma unroll
    for (int k = 0; k < 4; ++k) {
      const unsigned short u = f2bf((x[k] - mean) * rstd * w4[k] + b4[k]);
      Xh[row * 256 + k * 64 + lane] = u;
      *(unsigned short*)((char*)XT + (k * 64 + lane) * 136 + (w * 16 + rr) * 2) = u;
    }
  }
  __syncthreads();
#pragma unroll
  for (int fp = 0; fp < 4; ++fp) {
    const int f = fp * 64 + (t >> 2);
    const int jq = t & 3;
    uint2 v0 = *(const uint2*)((const char*)XT + f * 136 + jq * 32 + 0);
    uint2 v1 = *(const uint2*)((const char*)XT + f * 136 + jq * 32 + 8);
    uint2 v2 = *(const uint2*)((const char*)XT + f * 136 + jq * 32 + 16);
    uint2 v3 = *(const uint2*)((const char*)XT + f * 136 + jq * 32 + 24);
    unsigned short* dst = XhT + (b * 256 + f) * 4096 + j0 + jq * 16;
    *(uint4*)(dst) = make_uint4(v0.x, v0.y, v1.x, v1.y);
    *(uint4*)(dst + 8) = make_uint4(v2.x, v2.y, v3.x, v3.y);
  }
}

// ---------------------------------------------------------------------------
// svx[b][f] = sum_j xh[b][j][f]  (iteration-invariant)
__global__ __launch_bounds__(256) void k_sv(const unsigned short* __restrict__ XhT,
                                            float* __restrict__ svx) {
  const int b = blockIdx.x >> 2, fq = blockIdx.x & 3;
  const int lane = threadIdx.x & 63, w = threadIdx.x >> 6;
  for (int rr = 0; rr < 16; ++rr) {
    const int f = fq * 64 + w * 16 + rr;
    const unsigned short* p = XhT + ((long)(b * 256 + f)) * 4096;
    float s = 0.f;
#pragma unroll
    for (int i = 0; i < 8; ++i) {
      const uint4 v = *(const uint4*)(p + i * 512 + lane * 8);
      s += bf2f((unsigned short)(v.x & 0xffff)) + bf2f((unsigned short)(v.x >> 16)) +
           bf2f((unsigned short)(v.y & 0xffff)) + bf2f((unsigned short)(v.y >> 16)) +
           bf2f((unsigned short)(v.z & 0xffff)) + bf2f((unsigned short)(v.z >> 16)) +
           bf2f((unsigned short)(v.w & 0xffff)) + bf2f((unsigned short)(v.w >> 16));
    }
#pragma unroll
    for (int m = 1; m < 64; m <<= 1) s += __shfl_xor(s, m);
    if (lane == 0) svx[b * 256 + f] = s;
  }
}

// ---------------------------------------------------------------------------
// Initial q~: LN(slots) + q~[b][ih][f] via MT row-streams. Grid (64 b, 4 h).
__global__ __launch_bounds__(256) void k_q(
    const float* __restrict__ slots, const float* __restrict__ lnw,
    const float* __restrict__ lnb, const float* __restrict__ MT,
    unsigned short* __restrict__ qt) {
  __shared__ float sl[8 * 256];
  __shared__ float mstat[8], rstat[8];
  const int b = blockIdx.x, h = blockIdx.y, t = threadIdx.x;
#pragma unroll
  for (int i = 0; i < 8; ++i) sl[i * 256 + t] = slots[b * 2048 + i * 256 + t];
  __syncthreads();
  if (t < 8) {
    float s = 0.f, ss = 0.f;
    for (int k = 0; k < 256; ++k) {
      const float x = sl[t * 256 + k];
      s += x;
      ss += x * x;
    }
    const float m = s * (1.f / 256.f);
    mstat[t] = m;
    rstat[t] = rsqrtf(ss * (1.f / 256.f) - m * m + 1e-5f);
  }
  __syncthreads();
  const float w = lnw[t], bb = lnb[t];
#pragma unroll
  for (int i = 0; i < 8; ++i)
    sl[i * 256 + t] = (sl[i * 256 + t] - mstat[i]) * rstat[i] * w + bb;
  __syncthreads();
  float acc[8] = {};
  const float4* mrow = (const float4*)(MT + ((long)(h * 256 + t)) * 256);
#pragma unroll 4
  for (int D4 = 0; D4 < 64; ++D4) {
    const float4 m = mrow[D4];
#pragma unroll
    for (int i = 0; i < 8; ++i)
      acc[i] += dot4(*(const float4*)(sl + i * 256 + D4 * 4), m);
  }
#pragma unroll
  for (int i = 0; i < 8; ++i) {
    const int ih = i * 4 + h;
    *(unsigned short*)((char*)qt + b * 16384 + ih * 512 +
                       ((2 * t) ^ ((ih & 7) << 4))) = f2bf(acc[i]);
  }
}

// ---------------------------------------------------------------------------
// Barrier-free attention core (r10/r11, unchanged). Grid (8 jt, 64 b).
template <bool LAST>
__global__ __launch_bounds__(256) void k_att(
    const unsigned short* __restrict__ qt, const unsigned short* __restrict__ Xh,
    const unsigned short* __restrict__ XhT, float* __restrict__ upart,
    float* __restrict__ rowsum_part, float* __restrict__ attn_out) {
  __shared__ __align__(16) unsigned short Qs[32 * 256];
  __shared__ __align__(16) unsigned short Ps[4][1024];
  __shared__ float ured[4][2048];
  __shared__ float wred[4][32];
  const int t = threadIdx.x;
  const int lane = t & 63, wid = t >> 6;
  const int li = lane & 15, kg = lane >> 4;
  const int b = blockIdx.y;
  const long j0 = (long)blockIdx.x * 512 + wid * 128;

#pragma unroll
  for (int rnd = 0; rnd < 4; ++rnd)
    __builtin_amdgcn_global_load_lds(
        (const unsigned int*)((const char*)qt + b * 16384 + rnd * 4096 + t * 16),
        (unsigned int*)((char*)Qs + rnd * 4096 + t * 16), 16, 0, 0);
  __syncthreads();

  float rsum0 = 0.f, rsum1 = 0.f;
  f32x4 pv[2][16];
#pragma unroll
  for (int s = 0; s < 2; ++s)
#pragma unroll
    for (int ft = 0; ft < 16; ++ft) pv[s][ft] = (f32x4){0.f, 0.f, 0.f, 0.f};

  unsigned short* Pw = Ps[wid];

  for (int ch = 0; ch < 4; ++ch) {
    const long jc = j0 + ch * 32;
    f32x4 dacc[2][2];
    dacc[0][0] = (f32x4){0.f, 0.f, 0.f, 0.f};
    dacc[0][1] = (f32x4){0.f, 0.f, 0.f, 0.f};
    dacc[1][0] = (f32x4){0.f, 0.f, 0.f, 0.f};
    dacc[1][1] = (f32x4){0.f, 0.f, 0.f, 0.f};
#pragma unroll
    for (int jsub = 0; jsub < 2; ++jsub) {
      frag_ab kf[8];
      const unsigned short* kp =
          Xh + ((long)b * 4096 + jc + jsub * 16 + li) * 256 + kg * 8;
#pragma unroll
      for (int ks = 0; ks < 8; ++ks) kf[ks] = *(const frag_ab*)(kp + ks * 32);
#pragma unroll
      for (int g = 0; g < 2; ++g) {
        const char* qrow = (const char*)Qs + (g * 16 + li) * 512;
        const int swz = (li & 7) << 4;
#pragma unroll
        for (int ks = 0; ks < 8; ++ks) {
          const frag_ab qf = *(const frag_ab*)(qrow + ((ks * 64 + kg * 16) ^ swz));
          dacc[jsub][g] = __builtin_amdgcn_mfma_f32_16x16x32_bf16(
              kf[ks], qf, dacc[jsub][g], 0, 0, 0);
        }
      }
    }
    float p[2][2][4];
#pragma unroll
    for (int jsub = 0; jsub < 2; ++jsub) {
#pragma unroll
      for (int r = 0; r < 4; ++r) {
        const float d0 = dacc[jsub][0][r];
        const float d1 = dacc[jsub][1][r];
        float mx = fmaxf(d0, d1);
        mx = fmaxf(mx, __shfl_xor(mx, 1));
        mx = fmaxf(mx, __shfl_xor(mx, 2));
        mx = fmaxf(mx, __shfl_xor(mx, 4));
        mx = fmaxf(mx, __shfl_xor(mx, 8));
        float e0 = __expf(d0 - mx), e1 = __expf(d1 - mx);
        float sm = e0 + e1;
        sm += __shfl_xor(sm, 1);
        sm += __shfl_xor(sm, 2);
        sm += __shfl_xor(sm, 4);
        sm += __shfl_xor(sm, 8);
        const float inv = 1.f / sm;
        e0 *= inv;
        e1 *= inv;
        p[jsub][0][r] = e0;
        p[jsub][1][r] = e1;
        rsum0 += e0;
        rsum1 += e1;
        if (LAST) {
          float s0 = e0 + __shfl_xor(e0, 1);
          s0 += __shfl_xor(s0, 2);
          float s1 = e1 + __shfl_xor(e1, 1);
          s1 += __shfl_xor(s1, 2);
          if ((li & 3) == 0) {
            const long jg = jc + jsub * 16 + kg * 4 + r;
            attn_out[((long)b * 8 + (li >> 2)) * 4096 + jg] = s0 * 0.25f;
            attn_out[((long)b * 8 + 4 + (li >> 2)) * 4096 + jg] = s1 * 0.25f;
          }
        }
      }
    }
    asm volatile("s_waitcnt lgkmcnt(0)" ::: "memory");
#pragma unroll
    for (int g = 0; g < 2; ++g) {
      const int ih = g * 16 + li;
      char* prow = (char*)Pw + ih * 64;
      const int swz = ((ih >> 2) & 3) << 4;
#pragma unroll
      for (int jsub = 0; jsub < 2; ++jsub)
#pragma unroll
        for (int rp = 0; rp < 2; ++rp) {
          const unsigned int pk =
              (unsigned)f2bf(p[jsub][g][2 * rp]) |
              ((unsigned)f2bf(p[jsub][g][2 * rp + 1]) << 16);
          const int jb = (jsub * 16 + kg * 4 + 2 * rp) * 2;
          *(unsigned int*)(prow + (jb ^ swz)) = pk;
        }
    }
    asm volatile("s_waitcnt lgkmcnt(0)" ::: "memory");
    const frag_ab pa0 = *(const frag_ab*)(
        (const char*)Pw + li * 64 + ((kg * 16) ^ (((li >> 2) & 3) << 4)));
    const frag_ab pa1 = *(const frag_ab*)(
        (const char*)Pw + (16 + li) * 64 +
        ((kg * 16) ^ ((((16 + li) >> 2) & 3) << 4)));
#pragma unroll
    for (int ft = 0; ft < 16; ++ft) {
      const frag_ab vf = *(const frag_ab*)(
          XhT + ((long)b * 256 + ft * 16 + li) * 4096 + jc + kg * 8);
      pv[0][ft] = __builtin_amdgcn_mfma_f32_16x16x32_bf16(pa0, vf, pv[0][ft], 0, 0, 0);
      pv[1][ft] = __builtin_amdgcn_mfma_f32_16x16x32_bf16(pa1, vf, pv[1][ft], 0, 0, 0);
    }
  }

  rsum0 += __shfl_xor(rsum0, 16);
  rsum0 += __shfl_xor(rsum0, 32);
  rsum1 += __shfl_xor(rsum1, 16);
  rsum1 += __shfl_xor(rsum1, 32);
  if (lane < 16) {
    wred[wid][lane] = rsum0;
    wred[wid][16 + lane] = rsum1;
  }

  const long pb = (long)blockIdx.x * 64 + b;
#pragma unroll
  for (int p4 = 0; p4 < 4; ++p4) {
    __syncthreads();
    if ((kg >> 1) == (p4 & 1)) {
#pragma unroll
      for (int ft = 0; ft < 16; ++ft)
#pragma unroll
        for (int r = 0; r < 4; ++r)
          ured[wid][((kg & 1) * 4 + r) * 256 + ft * 16 + li] = pv[p4 >> 1][ft][r];
    }
    __syncthreads();
#pragma unroll
    for (int o = 0; o < 8; ++o) {
      const int idx = o * 256 + t;
      upart[(pb * 32 + p4 * 8 + o) * 256 + t] =
          ured[0][idx] + ured[1][idx] + ured[2][idx] + ured[3][idx];
    }
  }
  if (t < 32)
    rowsum_part[pb * 32 + t] = wred[0][t] + wred[1][t] + wred[2][t] + wred[3][t];
}

// ---------------------------------------------------------------------------
// Row-split fused tail, float4 row-stream edition. Grid (4 io, 64 b).
// Block owns slot rows i0=2io, i1=2io+1.
template <bool LAST>
__global__ __launch_bounds__(256) void k_tail(
    const float* __restrict__ upart, const float* __restrict__ svx,
    const float* __restrict__ rowsum_part, const float* __restrict__ wv,
    const float* __restrict__ wih, const float* __restrict__ whh,
    const float* __restrict__ bih, const float* __restrict__ bhh,
    const float* __restrict__ lnw, const float* __restrict__ lnb,
    const float* __restrict__ MT, float* __restrict__ slots,
    unsigned short* __restrict__ qt, float* __restrict__ dout) {
  __shared__ float xti[8][256];   // X~ rows ih = io*8 .. io*8+7
  __shared__ float upd[2][256];   // updates rows i0,i1; later snl rows
  __shared__ float hl[2][256];
  __shared__ float sn[2][256];
  __shared__ float rsl[8];
  __shared__ float mst[2], rst[2];
  const int t = threadIdx.x;
  const int io = blockIdx.x;
  const int b = blockIdx.y;
  const int i0 = io * 2, i1 = io * 2 + 1;

  if (t < 8) {
    float s2 = 0.f;
#pragma unroll
    for (int p = 0; p < 8; ++p)
      s2 += rowsum_part[((long)(p * 64 + b)) * 32 + io * 8 + t];
    rsl[t] = 1.f / (s2 + 4096.f * 1e-8f);
  }
  hl[0][t] = slots[b * 2048 + i0 * 256 + t];
  hl[1][t] = slots[b * 2048 + i1 * 256 + t];
  __syncthreads();
  // U-reduce + EPS renorm (rows ih = io*8+o, f = t)
  const float svf = svx[b * 256 + t] * 1e-8f;
#pragma unroll
  for (int o = 0; o < 8; ++o) {
    const int ih = io * 8 + o;
    float pp = 0.f;
#pragma unroll
    for (int p = 0; p < 8; ++p)
      pp += upart[(((long)(p * 64 + b)) * 32 + ih) * 256 + t];
    xti[o][t] = (pp + svf) * rsl[o];
  }
  __syncthreads();
  // Wv projection: thread t streams wv row t (f contiguous, float4)
  {
    const int h = t >> 6;  // wave-uniform -> xti reads broadcast
    const float4* wv4 = (const float4*)(wv + (long)t * 256);
    float a0 = 0.f, a1 = 0.f;
#pragma unroll 4
    for (int f4 = 0; f4 < 64; ++f4) {
      const float4 wvv = wv4[f4];
      a0 += dot4(wvv, *(const float4*)(&xti[h][f4 * 4]));
      a1 += dot4(wvv, *(const float4*)(&xti[4 + h][f4 * 4]));
    }
    upd[0][t] = a0;
    upd[1][t] = a1;
  }
  __syncthreads();
  // gates + combine at d = t: 6 weight row-streams (k contiguous, float4)
  float hn0, hn1;
  {
    const float4* wr4 = (const float4*)(wih + (long)t * 256);
    const float4* wz4 = (const float4*)(wih + (long)(256 + t) * 256);
    const float4* wn4 = (const float4*)(wih + (long)(512 + t) * 256);
    const float4* vr4 = (const float4*)(whh + (long)t * 256);
    const float4* vz4 = (const float4*)(whh + (long)(256 + t) * 256);
    const float4* vn4 = (const float4*)(whh + (long)(512 + t) * 256);
    float gir0 = 0, giz0 = 0, gin0 = 0, ghr0 = 0, ghz0 = 0, ghn0 = 0;
    float gir1 = 0, giz1 = 0, gin1 = 0, ghr1 = 0, ghz1 = 0, ghn1 = 0;
#pragma unroll 4
    for (int k4 = 0; k4 < 64; ++k4) {
      const float4 wr = wr4[k4], wz = wz4[k4], wn = wn4[k4];
      const float4 vr = vr4[k4], vz = vz4[k4], vn = vn4[k4];
      const float4 x0 = *(const float4*)(&upd[0][k4 * 4]);
      const float4 x1 = *(const float4*)(&upd[1][k4 * 4]);
      const float4 h0 = *(const float4*)(&hl[0][k4 * 4]);
      const float4 h1 = *(const float4*)(&hl[1][k4 * 4]);
      gir0 += dot4(x0, wr); giz0 += dot4(x0, wz); gin0 += dot4(x0, wn);
      ghr0 += dot4(h0, vr); ghz0 += dot4(h0, vz); ghn0 += dot4(h0, vn);
      gir1 += dot4(x1, wr); giz1 += dot4(x1, wz); gin1 += dot4(x1, wn);
      ghr1 += dot4(h1, vr); ghz1 += dot4(h1, vz); ghn1 += dot4(h1, vn);
    }
    const float br = bih[t], bz = bih[256 + t], bn = bih[512 + t];
    const float cr = bhh[t], cz = bhh[256 + t], cn = bhh[512 + t];
    const float r0 = 1.f / (1.f + __expf(-(gir0 + br + ghr0 + cr)));
    const float z0 = 1.f / (1.f + __expf(-(giz0 + bz + ghz0 + cz)));
    const float n0 = tanhf(gin0 + bn + r0 * (ghn0 + cn));
    hn0 = (1.f - z0) * n0 + z0 * hl[0][t];
    const float r1 = 1.f / (1.f + __expf(-(gir1 + br + ghr1 + cr)));
    const float z1 = 1.f / (1.f + __expf(-(giz1 + bz + ghz1 + cz)));
    const float n1 = tanhf(gin1 + bn + r1 * (ghn1 + cn));
    hn1 = (1.f - z1) * n1 + z1 * hl[1][t];
  }
  slots[b * 2048 + i0 * 256 + t] = hn0;
  slots[b * 2048 + i1 * 256 + t] = hn1;
  if (LAST) {
    dout[b * 2048 + i0 * 256 + t] = hn0;
    dout[b * 2048 + i1 * 256 + t] = hn1;
    return;
  }
  sn[0][t] = hn0;
  sn[1][t] = hn1;
  __syncthreads();
  // block-local LN stats
  {
    const int wv_ = t >> 6, lane = t & 63;
    if (wv_ < 2) {
      float s = 0.f, ss = 0.f;
#pragma unroll
      for (int u = 0; u < 4; ++u) {
        const float x = sn[wv_][u * 64 + lane];
        s += x;
        ss += x * x;
      }
#pragma unroll
      for (int m = 1; m < 64; m <<= 1) {
        s += __shfl_xor(s, m);
        ss += __shfl_xor(ss, m);
      }
      if (lane == 0) {
        const float mn = s * (1.f / 256.f);
        mst[wv_] = mn;
        rst[wv_] = rsqrtf(ss * (1.f / 256.f) - mn * mn + 1e-5f);
      }
    }
  }
  __syncthreads();
  upd[0][t] = (sn[0][t] - mst[0]) * rst[0] * lnw[t] + lnb[t];  // snl rows
  upd[1][t] = (sn[1][t] - mst[1]) * rst[1] * lnw[t] + lnb[t];
  __syncthreads();
  // q~: thread t (= f) streams MT rows (D contiguous), snl from LDS broadcast
  {
    float acc[8];
#pragma unroll
    for (int c = 0; c < 8; ++c) acc[c] = 0.f;
    const float4* m0 = (const float4*)(MT + ((long)(0 * 256 + t)) * 256);
    const float4* m1 = (const float4*)(MT + ((long)(1 * 256 + t)) * 256);
    const float4* m2 = (const float4*)(MT + ((long)(2 * 256 + t)) * 256);
    const float4* m3 = (const float4*)(MT + ((long)(3 * 256 + t)) * 256);
#pragma unroll 4
    for (int D4 = 0; D4 < 64; ++D4) {
      const float4 s0 = *(const float4*)(&upd[0][D4 * 4]);
      const float4 s1 = *(const float4*)(&upd[1][D4 * 4]);
      const float4 a = m0[D4], bq = m1[D4], c = m2[D4], d = m3[D4];
      acc[0] += dot4(s0, a);
      acc[1] += dot4(s0, bq);
      acc[2] += dot4(s0, c);
      acc[3] += dot4(s0, d);
      acc[4] += dot4(s1, a);
      acc[5] += dot4(s1, bq);
      acc[6] += dot4(s1, c);
      acc[7] += dot4(s1, d);
    }
#pragma unroll
    for (int c = 0; c < 8; ++c) {
      const int i = (c < 4) ? i0 : i1;
      const int h = c & 3;
      const int ih = i * 4 + h;
      *(unsigned short*)((char*)qt + b * 16384 + ih * 512 +
                         ((2 * t) ^ ((ih & 7) << 4))) = f2bf(acc[c]);
    }
  }
}

// ---------------------------------------------------------------------------
extern "C" void kernel_launch(void* const* d_in, const int* in_sizes, int n_in,
                              void* d_out, int out_size, void* d_ws,
                              size_t ws_size, hipStream_t stream) {
  const float* xin = (const float*)d_in[0];
  const float* cond = (const float*)d_in[1];
  const float* lnin_w = (const float*)d_in[2];
  const float* lnin_b = (const float*)d_in[3];
  const float* lns_w = (const float*)d_in[4];
  const float* lns_b = (const float*)d_in[5];
  const float* wq = (const float*)d_in[6];
  const float* wk = (const float*)d_in[7];
  const float* wv = (const float*)d_in[8];
  const float* gwih = (const float*)d_in[9];
  const float* gwhh = (const float*)d_in[10];
  const float* gbih = (const float*)d_in[11];
  const float* gbhh = (const float*)d_in[12];
  float* out = (float*)d_out;

  char* ws = (char*)d_ws;
  unsigned short* Xh = (unsigned short*)ws;   ws += 262144l * 256 * 2;      // 128MB
  unsigned short* XhT = (unsigned short*)ws;  ws += 64l * 256 * 4096 * 2;   // 128MB
  float* MT = (float*)ws;                     ws += 4l * 256 * 256 * 4;     // 1MB
  unsigned short* qt = (unsigned short*)ws;   ws += 64l * 32 * 256 * 2;     // 1MB
  float* upart = (float*)ws;                  ws += 8l * 64 * 32 * 256 * 4; // 16MB
  float* svx = (float*)ws;                    ws += 64l * 256 * 4;
  float* rowsum_part = (float*)ws;            ws += 8l * 64 * 32 * 4;
  float* slots = (float*)ws;                  ws += 512l * 256 * 4;
  // total ~275 MB

  hipMemcpyAsync(slots, cond, 512 * 256 * 4, hipMemcpyDeviceToDevice, stream);
  k_mprep<<<dim3(256, 4), 256, 0, stream>>>(wq, wk, MT);
  k_precvt<<<4096, 256, 0, stream>>>(xin, lnin_w, lnin_b, Xh, XhT);
  k_sv<<<256, 256, 0, stream>>>(XhT, svx);
  k_q<<<dim3(64, 4), 256, 0, stream>>>(slots, lns_w, lns_b, MT, qt);

  // iter 0
  k_att<false><<<dim3(8, 64), 256, 0, stream>>>(qt, Xh, XhT, upart,
                                                rowsum_part, out + 131072);
  k_tail<false><<<dim3(4, 64), 256, 0, stream>>>(
      upart, svx, rowsum_part, wv, gwih, gwhh, gbih, gbhh, lns_w, lns_b, MT,
      slots, qt, out);
  // iter 1
  k_att<false><<<dim3(8, 64), 256, 0, stream>>>(qt, Xh, XhT, upart,
                                                rowsum_part, out + 131072);
  k_tail<false><<<dim3(4, 64), 256, 0, stream>>>(
      upart, svx, rowsum_part, wv, gwih, gwhh, gbih, gbhh, lns_w, lns_b, MT,
      slots, qt, out);
  // iter 2
  k_att<true><<<dim3(8, 64), 256, 0, stream>>>(qt, Xh, XhT, upart,
                                               rowsum_part, out + 131072);
  k_tail<true><<<dim3(4, 64), 256, 0, stream>>>(
      upart, svx, rowsum_part, wv, gwih, gwhh, gbih, gbhh, lns_w, lns_b, MT,
      slots, qt, out);
}

// Round 13
// 655.146 us; speedup vs baseline: 1.2856x; 1.2261x over previous
//
#include <hip/hip_runtime.h>
#include <hip/hip_bf16.h>
#include <math.h>

// SlotAttention: B=64 N=4096 F=256 D=256 KVQ=256 H=4 S=8 DH=64 ITERS=3
// Round 13: tail split for TLP (k_xu 2048 blocks; k_gq 512x512 2 blk/CU) +
// bf16 weights (wih/whh/wv/MT) to halve L2 traffic and load counts.

using frag_ab = __attribute__((ext_vector_type(8))) short;   // 8 bf16
using f32x4  = __attribute__((ext_vector_type(4))) float;

__device__ __forceinline__ unsigned short f2bf(float f) {
  unsigned int x = __float_as_uint(f);
  x += 0x7fffu + ((x >> 16) & 1u);   // RNE
  return (unsigned short)(x >> 16);
}
__device__ __forceinline__ float bf2f(unsigned short u) {
  return __uint_as_float((unsigned int)u << 16);
}
__device__ __forceinline__ float dot8(const uint4 w, const float* __restrict__ x) {
  return bf2f((unsigned short)(w.x & 0xffff)) * x[0] +
         bf2f((unsigned short)(w.x >> 16)) * x[1] +
         bf2f((unsigned short)(w.y & 0xffff)) * x[2] +
         bf2f((unsigned short)(w.y >> 16)) * x[3] +
         bf2f((unsigned short)(w.z & 0xffff)) * x[4] +
         bf2f((unsigned short)(w.z >> 16)) * x[5] +
         bf2f((unsigned short)(w.w & 0xffff)) * x[6] +
         bf2f((unsigned short)(w.w >> 16)) * x[7];
}

// ---------------------------------------------------------------------------
// Convert wih, whh, wv to bf16 (same row layout, k contiguous).
__global__ __launch_bounds__(256) void k_wcvt2(const float* __restrict__ wih,
                                               const float* __restrict__ whh,
                                               const float* __restrict__ wv,
                                               unsigned short* __restrict__ wihB,
                                               unsigned short* __restrict__ whhB,
                                               unsigned short* __restrict__ wvB) {
  const long idx = (long)blockIdx.x * 1024 + threadIdx.x * 4;
  const float* src;
  unsigned short* dst;
  long off;
  if (idx < 196608) { src = wih; dst = wihB; off = idx; }
  else if (idx < 393216) { src = whh; dst = whhB; off = idx - 196608; }
  else { src = wv; dst = wvB; off = idx - 393216; }
  const float4 v = *(const float4*)(src + off);
  uint2 o;
  o.x = (unsigned)f2bf(v.x) | ((unsigned)f2bf(v.y) << 16);
  o.y = (unsigned)f2bf(v.z) | ((unsigned)f2bf(v.w) << 16);
  *(uint2*)(dst + off) = o;
}

// ---------------------------------------------------------------------------
// MTB[h][f][D] = bf16(SCALE * sum_d wq[h*64+d][D] * wk[h*64+d][f])
__global__ __launch_bounds__(256) void k_mprep(const float* __restrict__ wq,
                                               const float* __restrict__ wk,
                                               unsigned short* __restrict__ MTB) {
  const int f = blockIdx.x, h = blockIdx.y, D = threadIdx.x;
  float acc = 0.f;
#pragma unroll 8
  for (int d = 0; d < 64; ++d)
    acc += wq[(h * 64 + d) * 256 + D] * wk[(h * 64 + d) * 256 + f];
  MTB[((long)(h * 256 + f)) * 256 + D] = f2bf(acc * 0.125f);
}

// ---------------------------------------------------------------------------
// Pre-pass: dual-layout LN output (unchanged from r12).
__global__ __launch_bounds__(256) void k_precvt(
    const float* __restrict__ xsrc, const float* __restrict__ lnw,
    const float* __restrict__ lnb, unsigned short* __restrict__ Xh,
    unsigned short* __restrict__ XhT) {
  __shared__ __align__(16) unsigned short XT[256 * 68];  // row stride 136B
  const int t = threadIdx.x;
  const int lane = t & 63, w = t >> 6;
  const long row0 = (long)blockIdx.x * 64;
  const long b = row0 >> 12;
  const long j0 = row0 & 4095;

  float w4[4], b4[4];
#pragma unroll
  for (int k = 0; k < 4; ++k) {
    w4[k] = lnw[k * 64 + lane];
    b4[k] = lnb[k * 64 + lane];
  }
  for (int rr = 0; rr < 16; ++rr) {
    const long row = row0 + w * 16 + rr;
    float x[4];
    float s = 0.f, ss = 0.f;
#pragma unroll
    for (int k = 0; k < 4; ++k) {
      x[k] = xsrc[row * 256 + k * 64 + lane];
      s += x[k];
      ss += x[k] * x[k];
    }
#pragma unroll
    for (int m = 1; m < 64; m <<= 1) {
      s += __shfl_xor(s, m);
      ss += __shfl_xor(ss, m);
    }
    const float mean = s * (1.f / 256.f);
    const float rstd = rsqrtf(ss * (1.f / 256.f) - mean * mean + 1e-5f);
#pragma unroll
    for (int k = 0; k < 4; ++k) {
      const unsigned short u = f2bf((x[k] - mean) * rstd * w4[k] + b4[k]);
      Xh[row * 256 + k * 64 + lane] = u;
      *(unsigned short*)((char*)XT + (k * 64 + lane) * 136 + (w * 16 + rr) * 2) = u;
    }
  }
  __syncthreads();
#pragma unroll
  for (int fp = 0; fp < 4; ++fp) {
    const int f = fp * 64 + (t >> 2);
    const int jq = t & 3;
    uint2 v0 = *(const uint2*)((const char*)XT + f * 136 + jq * 32 + 0);
    uint2 v1 = *(const uint2*)((const char*)XT + f * 136 + jq * 32 + 8);
    uint2 v2 = *(const uint2*)((const char*)XT + f * 136 + jq * 32 + 16);
    uint2 v3 = *(const uint2*)((const char*)XT + f * 136 + jq * 32 + 24);
    unsigned short* dst = XhT + (b * 256 + f) * 4096 + j0 + jq * 16;
    *(uint4*)(dst) = make_uint4(v0.x, v0.y, v1.x, v1.y);
    *(uint4*)(dst + 8) = make_uint4(v2.x, v2.y, v3.x, v3.y);
  }
}

// ---------------------------------------------------------------------------
// svx[b][f] = sum_j xh[b][j][f]  (iteration-invariant)
__global__ __launch_bounds__(256) void k_sv(const unsigned short* __restrict__ XhT,
                                            float* __restrict__ svx) {
  const int b = blockIdx.x >> 2, fq = blockIdx.x & 3;
  const int lane = threadIdx.x & 63, w = threadIdx.x >> 6;
  for (int rr = 0; rr < 16; ++rr) {
    const int f = fq * 64 + w * 16 + rr;
    const unsigned short* p = XhT + ((long)(b * 256 + f)) * 4096;
    float s = 0.f;
#pragma unroll
    for (int i = 0; i < 8; ++i) {
      const uint4 v = *(const uint4*)(p + i * 512 + lane * 8);
      s += bf2f((unsigned short)(v.x & 0xffff)) + bf2f((unsigned short)(v.x >> 16)) +
           bf2f((unsigned short)(v.y & 0xffff)) + bf2f((unsigned short)(v.y >> 16)) +
           bf2f((unsigned short)(v.z & 0xffff)) + bf2f((unsigned short)(v.z >> 16)) +
           bf2f((unsigned short)(v.w & 0xffff)) + bf2f((unsigned short)(v.w >> 16));
    }
#pragma unroll
    for (int m = 1; m < 64; m <<= 1) s += __shfl_xor(s, m);
    if (lane == 0) svx[b * 256 + f] = s;
  }
}

// ---------------------------------------------------------------------------
// Initial q~: LN(slots) + q~ via MTB row-streams. Grid (64 b, 4 h).
__global__ __launch_bounds__(256) void k_q(
    const float* __restrict__ slots, const float* __restrict__ lnw,
    const float* __restrict__ lnb, const unsigned short* __restrict__ MTB,
    unsigned short* __restrict__ qt) {
  __shared__ float sl[8 * 256];
  __shared__ float mstat[8], rstat[8];
  const int b = blockIdx.x, h = blockIdx.y, t = threadIdx.x;
#pragma unroll
  for (int i = 0; i < 8; ++i) sl[i * 256 + t] = slots[b * 2048 + i * 256 + t];
  __syncthreads();
  if (t < 8) {
    float s = 0.f, ss = 0.f;
    for (int k = 0; k < 256; ++k) {
      const float x = sl[t * 256 + k];
      s += x;
      ss += x * x;
    }
    const float m = s * (1.f / 256.f);
    mstat[t] = m;
    rstat[t] = rsqrtf(ss * (1.f / 256.f) - m * m + 1e-5f);
  }
  __syncthreads();
  const float w = lnw[t], bb = lnb[t];
#pragma unroll
  for (int i = 0; i < 8; ++i)
    sl[i * 256 + t] = (sl[i * 256 + t] - mstat[i]) * rstat[i] * w + bb;
  __syncthreads();
  float acc[8] = {};
  const uint4* mrow = (const uint4*)(MTB + ((long)(h * 256 + t)) * 256);
#pragma unroll 4
  for (int D8 = 0; D8 < 32; ++D8) {
    const uint4 m = mrow[D8];
#pragma unroll
    for (int i = 0; i < 8; ++i) acc[i] += dot8(m, sl + i * 256 + D8 * 8);
  }
#pragma unroll
  for (int i = 0; i < 8; ++i) {
    const int ih = i * 4 + h;
    *(unsigned short*)((char*)qt + b * 16384 + ih * 512 +
                       ((2 * t) ^ ((ih & 7) << 4))) = f2bf(acc[i]);
  }
}

// ---------------------------------------------------------------------------
// Barrier-free attention core (unchanged). Grid (8 jt, 64 b).
template <bool LAST>
__global__ __launch_bounds__(256) void k_att(
    const unsigned short* __restrict__ qt, const unsigned short* __restrict__ Xh,
    const unsigned short* __restrict__ XhT, float* __restrict__ upart,
    float* __restrict__ rowsum_part, float* __restrict__ attn_out) {
  __shared__ __align__(16) unsigned short Qs[32 * 256];
  __shared__ __align__(16) unsigned short Ps[4][1024];
  __shared__ float ured[4][2048];
  __shared__ float wred[4][32];
  const int t = threadIdx.x;
  const int lane = t & 63, wid = t >> 6;
  const int li = lane & 15, kg = lane >> 4;
  const int b = blockIdx.y;
  const long j0 = (long)blockIdx.x * 512 + wid * 128;

#pragma unroll
  for (int rnd = 0; rnd < 4; ++rnd)
    __builtin_amdgcn_global_load_lds(
        (const unsigned int*)((const char*)qt + b * 16384 + rnd * 4096 + t * 16),
        (unsigned int*)((char*)Qs + rnd * 4096 + t * 16), 16, 0, 0);
  __syncthreads();

  float rsum0 = 0.f, rsum1 = 0.f;
  f32x4 pv[2][16];
#pragma unroll
  for (int s = 0; s < 2; ++s)
#pragma unroll
    for (int ft = 0; ft < 16; ++ft) pv[s][ft] = (f32x4){0.f, 0.f, 0.f, 0.f};

  unsigned short* Pw = Ps[wid];

  for (int ch = 0; ch < 4; ++ch) {
    const long jc = j0 + ch * 32;
    f32x4 dacc[2][2];
    dacc[0][0] = (f32x4){0.f, 0.f, 0.f, 0.f};
    dacc[0][1] = (f32x4){0.f, 0.f, 0.f, 0.f};
    dacc[1][0] = (f32x4){0.f, 0.f, 0.f, 0.f};
    dacc[1][1] = (f32x4){0.f, 0.f, 0.f, 0.f};
#pragma unroll
    for (int jsub = 0; jsub < 2; ++jsub) {
      frag_ab kf[8];
      const unsigned short* kp =
          Xh + ((long)b * 4096 + jc + jsub * 16 + li) * 256 + kg * 8;
#pragma unroll
      for (int ks = 0; ks < 8; ++ks) kf[ks] = *(const frag_ab*)(kp + ks * 32);
#pragma unroll
      for (int g = 0; g < 2; ++g) {
        const char* qrow = (const char*)Qs + (g * 16 + li) * 512;
        const int swz = (li & 7) << 4;
#pragma unroll
        for (int ks = 0; ks < 8; ++ks) {
          const frag_ab qf = *(const frag_ab*)(qrow + ((ks * 64 + kg * 16) ^ swz));
          dacc[jsub][g] = __builtin_amdgcn_mfma_f32_16x16x32_bf16(
              kf[ks], qf, dacc[jsub][g], 0, 0, 0);
        }
      }
    }
    float p[2][2][4];
#pragma unroll
    for (int jsub = 0; jsub < 2; ++jsub) {
#pragma unroll
      for (int r = 0; r < 4; ++r) {
        const float d0 = dacc[jsub][0][r];
        const float d1 = dacc[jsub][1][r];
        float mx = fmaxf(d0, d1);
        mx = fmaxf(mx, __shfl_xor(mx, 1));
        mx = fmaxf(mx, __shfl_xor(mx, 2));
        mx = fmaxf(mx, __shfl_xor(mx, 4));
        mx = fmaxf(mx, __shfl_xor(mx, 8));
        float e0 = __expf(d0 - mx), e1 = __expf(d1 - mx);
        float sm = e0 + e1;
        sm += __shfl_xor(sm, 1);
        sm += __shfl_xor(sm, 2);
        sm += __shfl_xor(sm, 4);
        sm += __shfl_xor(sm, 8);
        const float inv = 1.f / sm;
        e0 *= inv;
        e1 *= inv;
        p[jsub][0][r] = e0;
        p[jsub][1][r] = e1;
        rsum0 += e0;
        rsum1 += e1;
        if (LAST) {
          float s0 = e0 + __shfl_xor(e0, 1);
          s0 += __shfl_xor(s0, 2);
          float s1 = e1 + __shfl_xor(e1, 1);
          s1 += __shfl_xor(s1, 2);
          if ((li & 3) == 0) {
            const long jg = jc + jsub * 16 + kg * 4 + r;
            attn_out[((long)b * 8 + (li >> 2)) * 4096 + jg] = s0 * 0.25f;
            attn_out[((long)b * 8 + 4 + (li >> 2)) * 4096 + jg] = s1 * 0.25f;
          }
        }
      }
    }
    asm volatile("s_waitcnt lgkmcnt(0)" ::: "memory");
#pragma unroll
    for (int g = 0; g < 2; ++g) {
      const int ih = g * 16 + li;
      char* prow = (char*)Pw + ih * 64;
      const int swz = ((ih >> 2) & 3) << 4;
#pragma unroll
      for (int jsub = 0; jsub < 2; ++jsub)
#pragma unroll
        for (int rp = 0; rp < 2; ++rp) {
          const unsigned int pk =
              (unsigned)f2bf(p[jsub][g][2 * rp]) |
              ((unsigned)f2bf(p[jsub][g][2 * rp + 1]) << 16);
          const int jb = (jsub * 16 + kg * 4 + 2 * rp) * 2;
          *(unsigned int*)(prow + (jb ^ swz)) = pk;
        }
    }
    asm volatile("s_waitcnt lgkmcnt(0)" ::: "memory");
    const frag_ab pa0 = *(const frag_ab*)(
        (const char*)Pw + li * 64 + ((kg * 16) ^ (((li >> 2) & 3) << 4)));
    const frag_ab pa1 = *(const frag_ab*)(
        (const char*)Pw + (16 + li) * 64 +
        ((kg * 16) ^ ((((16 + li) >> 2) & 3) << 4)));
#pragma unroll
    for (int ft = 0; ft < 16; ++ft) {
      const frag_ab vf = *(const frag_ab*)(
          XhT + ((long)b * 256 + ft * 16 + li) * 4096 + jc + kg * 8);
      pv[0][ft] = __builtin_amdgcn_mfma_f32_16x16x32_bf16(pa0, vf, pv[0][ft], 0, 0, 0);
      pv[1][ft] = __builtin_amdgcn_mfma_f32_16x16x32_bf16(pa1, vf, pv[1][ft], 0, 0, 0);
    }
  }

  rsum0 += __shfl_xor(rsum0, 16);
  rsum0 += __shfl_xor(rsum0, 32);
  rsum1 += __shfl_xor(rsum1, 16);
  rsum1 += __shfl_xor(rsum1, 32);
  if (lane < 16) {
    wred[wid][lane] = rsum0;
    wred[wid][16 + lane] = rsum1;
  }

  const long pb = (long)blockIdx.x * 64 + b;
#pragma unroll
  for (int p4 = 0; p4 < 4; ++p4) {
    __syncthreads();
    if ((kg >> 1) == (p4 & 1)) {
#pragma unroll
      for (int ft = 0; ft < 16; ++ft)
#pragma unroll
        for (int r = 0; r < 4; ++r)
          ured[wid][((kg & 1) * 4 + r) * 256 + ft * 16 + li] = pv[p4 >> 1][ft][r];
    }
    __syncthreads();
#pragma unroll
    for (int o = 0; o < 8; ++o) {
      const int idx = o * 256 + t;
      upart[(pb * 32 + p4 * 8 + o) * 256 + t] =
          ured[0][idx] + ured[1][idx] + ured[2][idx] + ured[3][idx];
    }
  }
  if (t < 32)
    rowsum_part[pb * 32 + t] = wred[0][t] + wred[1][t] + wred[2][t] + wred[3][t];
}

// ---------------------------------------------------------------------------
// U-reduce + EPS renorm. Grid (32 ih, 64 b) = 2048 blocks; t = f.
__global__ __launch_bounds__(256) void k_xu(
    const float* __restrict__ upart, const float* __restrict__ svx,
    const float* __restrict__ rowsum_part, float* __restrict__ xu) {
  const int t = threadIdx.x;
  const int ih = blockIdx.x;
  const int b = blockIdx.y;
  float s2 = 0.f;
#pragma unroll
  for (int p = 0; p < 8; ++p)
    s2 += rowsum_part[((long)(p * 64 + b)) * 32 + ih];   // wave-uniform s_loads
  const float rs = 1.f / (s2 + 4096.f * 1e-8f);
  float pp = 0.f;
#pragma unroll
  for (int p = 0; p < 8; ++p)
    pp += upart[(((long)(p * 64 + b)) * 32 + ih) * 256 + t];
  xu[((long)(b * 32 + ih)) * 256 + t] = (pp + svx[b * 256 + t] * 1e-8f) * rs;
}

// ---------------------------------------------------------------------------
// Per-(b,i) tail: Wv -> gates -> combine -> LN -> q~. Grid (8 i, 64 b),
// 512 threads, 2 blocks/CU. bf16 weights, fp32 accum.
template <bool LAST>
__global__ __launch_bounds__(512, 4) void k_gq(
    const float* __restrict__ xu, const unsigned short* __restrict__ wvB,
    const unsigned short* __restrict__ wihB, const unsigned short* __restrict__ whhB,
    const float* __restrict__ bih, const float* __restrict__ bhh,
    const float* __restrict__ lnw, const float* __restrict__ lnb,
    const unsigned short* __restrict__ MTB, float* __restrict__ slots,
    unsigned short* __restrict__ qt, float* __restrict__ dout) {
  __shared__ float xul[4][256];   // xu rows ih = i*4+h; xul[0] reused for hn
  __shared__ float hl[256];
  __shared__ float up2[2][256];
  __shared__ float updF[256];
  __shared__ float gI[3][256], gH[3][256];
  __shared__ float snl[256];
  __shared__ float mr[2];
  const int t = threadIdx.x;
  const int i = blockIdx.x;
  const int b = blockIdx.y;
  const int f = t & 255, half = t >> 8;

  // load h row + 4 xu rows
  if (t < 256) hl[t] = slots[b * 2048 + i * 256 + t];
#pragma unroll
  for (int hh = 0; hh < 2; ++hh) {
    const int row = half * 2 + hh;
    xul[row][f] = xu[((long)(b * 32 + i * 4 + row)) * 256 + f];
  }
  __syncthreads();
  // Wv: updates[gd] = sum_f wv[gd][f] * xul[gd>>6][f], split over 2 halves
  {
    const float* xr = xul[f >> 6];
    const uint4* wr = (const uint4*)(wvB + (long)f * 256 + half * 128);
    float a = 0.f;
#pragma unroll 4
    for (int k8 = 0; k8 < 16; ++k8) a += dot8(wr[k8], xr + half * 128 + k8 * 8);
    up2[half][f] = a;
  }
  __syncthreads();
  if (t < 256) updF[t] = up2[0][t] + up2[1][t];
  __syncthreads();
  // gates: col t for all; col 512+t for t<256
  {
    const int c = t;
    const uint4* wi = (const uint4*)(wihB + (long)c * 256);
    const uint4* wh = (const uint4*)(whhB + (long)c * 256);
    float gi = 0.f, gh = 0.f;
#pragma unroll 4
    for (int k8 = 0; k8 < 32; ++k8) {
      gi += dot8(wi[k8], updF + k8 * 8);
      gh += dot8(wh[k8], hl + k8 * 8);
    }
    gI[c >> 8][c & 255] = gi + bih[c];
    gH[c >> 8][c & 255] = gh + bhh[c];
  }
  if (t < 256) {
    const int c = 512 + t;
    const uint4* wi = (const uint4*)(wihB + (long)c * 256);
    const uint4* wh = (const uint4*)(whhB + (long)c * 256);
    float gi = 0.f, gh = 0.f;
#pragma unroll 4
    for (int k8 = 0; k8 < 32; ++k8) {
      gi += dot8(wi[k8], updF + k8 * 8);
      gh += dot8(wh[k8], hl + k8 * 8);
    }
    gI[2][t] = gi + bih[c];
    gH[2][t] = gh + bhh[c];
  }
  __syncthreads();
  // combine
  if (t < 256) {
    const float r = 1.f / (1.f + __expf(-(gI[0][t] + gH[0][t])));
    const float z = 1.f / (1.f + __expf(-(gI[1][t] + gH[1][t])));
    const float n = tanhf(gI[2][t] + r * gH[2][t]);
    const float hn = (1.f - z) * n + z * hl[t];
    slots[b * 2048 + i * 256 + t] = hn;
    if (LAST) dout[b * 2048 + i * 256 + t] = hn;
    xul[0][t] = hn;   // sn
  }
  if (LAST) return;
  __syncthreads();
  // block-local LN over xul[0]
  if (t < 64) {
    float s = 0.f, ss = 0.f;
#pragma unroll
    for (int u = 0; u < 4; ++u) {
      const float x = xul[0][u * 64 + t];
      s += x;
      ss += x * x;
    }
#pragma unroll
    for (int m = 1; m < 64; m <<= 1) {
      s += __shfl_xor(s, m);
      ss += __shfl_xor(ss, m);
    }
    if (t == 0) {
      const float mn = s * (1.f / 256.f);
      mr[0] = mn;
      mr[1] = rsqrtf(ss * (1.f / 256.f) - mn * mn + 1e-5f);
    }
  }
  __syncthreads();
  if (t < 256) snl[t] = (xul[0][t] - mr[0]) * mr[1] * lnw[t] + lnb[t];
  __syncthreads();
  // q~: thread handles (h = half*2 + hh, f): sum over 256 D via MTB rows
#pragma unroll
  for (int hh = 0; hh < 2; ++hh) {
    const int h = half * 2 + hh;
    const uint4* m = (const uint4*)(MTB + ((long)(h * 256 + f)) * 256);
    float acc = 0.f;
#pragma unroll 4
    for (int D8 = 0; D8 < 32; ++D8) acc += dot8(m[D8], snl + D8 * 8);
    const int ih = i * 4 + h;
    *(unsigned short*)((char*)qt + b * 16384 + ih * 512 +
                       ((2 * f) ^ ((ih & 7) << 4))) = f2bf(acc);
  }
}

// ---------------------------------------------------------------------------
extern "C" void kernel_launch(void* const* d_in, const int* in_sizes, int n_in,
                              void* d_out, int out_size, void* d_ws,
                              size_t ws_size, hipStream_t stream) {
  const float* xin = (const float*)d_in[0];
  const float* cond = (const float*)d_in[1];
  const float* lnin_w = (const float*)d_in[2];
  const float* lnin_b = (const float*)d_in[3];
  const float* lns_w = (const float*)d_in[4];
  const float* lns_b = (const float*)d_in[5];
  const float* wq = (const float*)d_in[6];
  const float* wk = (const float*)d_in[7];
  const float* wv = (const float*)d_in[8];
  const float* gwih = (const float*)d_in[9];
  const float* gwhh = (const float*)d_in[10];
  const float* gbih = (const float*)d_in[11];
  const float* gbhh = (const float*)d_in[12];
  float* out = (float*)d_out;

  char* ws = (char*)d_ws;
  unsigned short* Xh = (unsigned short*)ws;   ws += 262144l * 256 * 2;      // 128MB
  unsigned short* XhT = (unsigned short*)ws;  ws += 64l * 256 * 4096 * 2;   // 128MB
  unsigned short* MTB = (unsigned short*)ws;  ws += 4l * 256 * 256 * 2;
  unsigned short* qt = (unsigned short*)ws;   ws += 64l * 32 * 256 * 2;
  float* upart = (float*)ws;                  ws += 8l * 64 * 32 * 256 * 4; // 16MB
  float* svx = (float*)ws;                    ws += 64l * 256 * 4;
  float* rowsum_part = (float*)ws;            ws += 8l * 64 * 32 * 4;
  float* xu = (float*)ws;                     ws += 64l * 32 * 256 * 4;     // 2MB
  float* slots = (float*)ws;                  ws += 512l * 256 * 4;
  unsigned short* wihB = (unsigned short*)ws; ws += 768l * 256 * 2;
  unsigned short* whhB = (unsigned short*)ws; ws += 768l * 256 * 2;
  unsigned short* wvB = (unsigned short*)ws;  ws += 256l * 256 * 2;
  // total ~277 MB

  hipMemcpyAsync(slots, cond, 512 * 256 * 4, hipMemcpyDeviceToDevice, stream);
  k_wcvt2<<<448, 256, 0, stream>>>(gwih, gwhh, wv, wihB, whhB, wvB);
  k_mprep<<<dim3(256, 4), 256, 0, stream>>>(wq, wk, MTB);
  k_precvt<<<4096, 256, 0, stream>>>(xin, lnin_w, lnin_b, Xh, XhT);
  k_sv<<<256, 256, 0, stream>>>(XhT, svx);
  k_q<<<dim3(64, 4), 256, 0, stream>>>(slots, lns_w, lns_b, MTB, qt);

  // iter 0
  k_att<false><<<dim3(8, 64), 256, 0, stream>>>(qt, Xh, XhT, upart,
                                                rowsum_part, out + 131072);
  k_xu<<<dim3(32, 64), 256, 0, stream>>>(upart, svx, rowsum_part, xu);
  k_gq<false><<<dim3(8, 64), 512, 0, stream>>>(xu, wvB, wihB, whhB, gbih, gbhh,
                                               lns_w, lns_b, MTB, slots, qt, out);
  // iter 1
  k_att<false><<<dim3(8, 64), 256, 0, stream>>>(qt, Xh, XhT, upart,
                                                rowsum_part, out + 131072);
  k_xu<<<dim3(32, 64), 256, 0, stream>>>(upart, svx, rowsum_part, xu);
  k_gq<false><<<dim3(8, 64), 512, 0, stream>>>(xu, wvB, wihB, whhB, gbih, gbhh,
                                               lns_w, lns_b, MTB, slots, qt, out);
  // iter 2
  k_att<true><<<dim3(8, 64), 256, 0, stream>>>(qt, Xh, XhT, upart,
                                               rowsum_part, out + 131072);
  k_xu<<<dim3(32, 64), 256, 0, stream>>>(upart, svx, rowsum_part, xu);
  k_gq<true><<<dim3(8, 64), 512, 0, stream>>>(xu, wvB, wihB, whhB, gbih, gbhh,
                                              lns_w, lns_b, MTB, slots, qt, out);
}

// Round 14
// 628.975 us; speedup vs baseline: 1.3391x; 1.0416x over previous
//
#include <hip/hip_runtime.h>
#include <hip/hip_bf16.h>
#include <math.h>

// SlotAttention: B=64 N=4096 F=256 D=256 KVQ=256 H=4 S=8 DH=64 ITERS=3
// Round 14: r13 + (1) k_xu fused into k_gq, (2) tanhf -> exp-based, clamped,
// (3) sum_j xh fused into k_precvt as per-block partials + k_svr reduce.

using frag_ab = __attribute__((ext_vector_type(8))) short;   // 8 bf16
using f32x4  = __attribute__((ext_vector_type(4))) float;

__device__ __forceinline__ unsigned short f2bf(float f) {
  unsigned int x = __float_as_uint(f);
  x += 0x7fffu + ((x >> 16) & 1u);   // RNE
  return (unsigned short)(x >> 16);
}
__device__ __forceinline__ float bf2f(unsigned short u) {
  return __uint_as_float((unsigned int)u << 16);
}
__device__ __forceinline__ float dot8(const uint4 w, const float* __restrict__ x) {
  return bf2f((unsigned short)(w.x & 0xffff)) * x[0] +
         bf2f((unsigned short)(w.x >> 16)) * x[1] +
         bf2f((unsigned short)(w.y & 0xffff)) * x[2] +
         bf2f((unsigned short)(w.y >> 16)) * x[3] +
         bf2f((unsigned short)(w.z & 0xffff)) * x[4] +
         bf2f((unsigned short)(w.z >> 16)) * x[5] +
         bf2f((unsigned short)(w.w & 0xffff)) * x[6] +
         bf2f((unsigned short)(w.w >> 16)) * x[7];
}
__device__ __forceinline__ float fast_tanh(float x) {
  const float xc = fminf(fmaxf(x, -15.f), 15.f);
  const float e2 = __expf(2.f * xc);
  return (e2 - 1.f) / (e2 + 1.f);
}

// ---------------------------------------------------------------------------
// Convert wih, whh, wv to bf16 (same row layout, k contiguous).
__global__ __launch_bounds__(256) void k_wcvt2(const float* __restrict__ wih,
                                               const float* __restrict__ whh,
                                               const float* __restrict__ wv,
                                               unsigned short* __restrict__ wihB,
                                               unsigned short* __restrict__ whhB,
                                               unsigned short* __restrict__ wvB) {
  const long idx = (long)blockIdx.x * 1024 + threadIdx.x * 4;
  const float* src;
  unsigned short* dst;
  long off;
  if (idx < 196608) { src = wih; dst = wihB; off = idx; }
  else if (idx < 393216) { src = whh; dst = whhB; off = idx - 196608; }
  else { src = wv; dst = wvB; off = idx - 393216; }
  const float4 v = *(const float4*)(src + off);
  uint2 o;
  o.x = (unsigned)f2bf(v.x) | ((unsigned)f2bf(v.y) << 16);
  o.y = (unsigned)f2bf(v.z) | ((unsigned)f2bf(v.w) << 16);
  *(uint2*)(dst + off) = o;
}

// ---------------------------------------------------------------------------
// MTB[h][f][D] = bf16(SCALE * sum_d wq[h*64+d][D] * wk[h*64+d][f])
__global__ __launch_bounds__(256) void k_mprep(const float* __restrict__ wq,
                                               const float* __restrict__ wk,
                                               unsigned short* __restrict__ MTB) {
  const int f = blockIdx.x, h = blockIdx.y, D = threadIdx.x;
  float acc = 0.f;
#pragma unroll 8
  for (int d = 0; d < 64; ++d)
    acc += wq[(h * 64 + d) * 256 + D] * wk[(h * 64 + d) * 256 + f];
  MTB[((long)(h * 256 + f)) * 256 + D] = f2bf(acc * 0.125f);
}

// ---------------------------------------------------------------------------
// Pre-pass: dual-layout LN output + per-block sum_j partials.
__global__ __launch_bounds__(256) void k_precvt(
    const float* __restrict__ xsrc, const float* __restrict__ lnw,
    const float* __restrict__ lnb, unsigned short* __restrict__ Xh,
    unsigned short* __restrict__ XhT, float* __restrict__ svp) {
  __shared__ __align__(16) unsigned short XT[256 * 68];  // row stride 136B
  __shared__ float svred[4][256];
  const int t = threadIdx.x;
  const int lane = t & 63, w = t >> 6;
  const long row0 = (long)blockIdx.x * 64;
  const long b = row0 >> 12;
  const long j0 = row0 & 4095;

  float w4[4], b4[4];
#pragma unroll
  for (int k = 0; k < 4; ++k) {
    w4[k] = lnw[k * 64 + lane];
    b4[k] = lnb[k * 64 + lane];
  }
  float sacc[4] = {0.f, 0.f, 0.f, 0.f};
  for (int rr = 0; rr < 16; ++rr) {
    const long row = row0 + w * 16 + rr;
    float x[4];
    float s = 0.f, ss = 0.f;
#pragma unroll
    for (int k = 0; k < 4; ++k) {
      x[k] = xsrc[row * 256 + k * 64 + lane];
      s += x[k];
      ss += x[k] * x[k];
    }
#pragma unroll
    for (int m = 1; m < 64; m <<= 1) {
      s += __shfl_xor(s, m);
      ss += __shfl_xor(ss, m);
    }
    const float mean = s * (1.f / 256.f);
    const float rstd = rsqrtf(ss * (1.f / 256.f) - mean * mean + 1e-5f);
#pragma unroll
    for (int k = 0; k < 4; ++k) {
      const float xl = (x[k] - mean) * rstd * w4[k] + b4[k];
      sacc[k] += xl;
      const unsigned short u = f2bf(xl);
      Xh[row * 256 + k * 64 + lane] = u;
      *(unsigned short*)((char*)XT + (k * 64 + lane) * 136 + (w * 16 + rr) * 2) = u;
    }
  }
#pragma unroll
  for (int k = 0; k < 4; ++k) svred[w][k * 64 + lane] = sacc[k];
  __syncthreads();
  svp[(long)blockIdx.x * 256 + t] =
      svred[0][t] + svred[1][t] + svred[2][t] + svred[3][t];
#pragma unroll
  for (int fp = 0; fp < 4; ++fp) {
    const int f = fp * 64 + (t >> 2);
    const int jq = t & 3;
    uint2 v0 = *(const uint2*)((const char*)XT + f * 136 + jq * 32 + 0);
    uint2 v1 = *(const uint2*)((const char*)XT + f * 136 + jq * 32 + 8);
    uint2 v2 = *(const uint2*)((const char*)XT + f * 136 + jq * 32 + 16);
    uint2 v3 = *(const uint2*)((const char*)XT + f * 136 + jq * 32 + 24);
    unsigned short* dst = XhT + (b * 256 + f) * 4096 + j0 + jq * 16;
    *(uint4*)(dst) = make_uint4(v0.x, v0.y, v1.x, v1.y);
    *(uint4*)(dst + 8) = make_uint4(v2.x, v2.y, v3.x, v3.y);
  }
}

// ---------------------------------------------------------------------------
// svx[b][f] = sum over the 64 chunk partials (fixed order, deterministic).
__global__ __launch_bounds__(256) void k_svr(const float* __restrict__ svp,
                                             float* __restrict__ svx) {
  const int b = blockIdx.x, t = threadIdx.x;
  float s = 0.f;
#pragma unroll 8
  for (int c = 0; c < 64; ++c) s += svp[((long)(b * 64 + c)) * 256 + t];
  svx[b * 256 + t] = s;
}

// ---------------------------------------------------------------------------
// Initial q~: LN(slots) + q~ via MTB row-streams. Grid (64 b, 4 h).
__global__ __launch_bounds__(256) void k_q(
    const float* __restrict__ slots, const float* __restrict__ lnw,
    const float* __restrict__ lnb, const unsigned short* __restrict__ MTB,
    unsigned short* __restrict__ qt) {
  __shared__ float sl[8 * 256];
  __shared__ float mstat[8], rstat[8];
  const int b = blockIdx.x, h = blockIdx.y, t = threadIdx.x;
#pragma unroll
  for (int i = 0; i < 8; ++i) sl[i * 256 + t] = slots[b * 2048 + i * 256 + t];
  __syncthreads();
  if (t < 8) {
    float s = 0.f, ss = 0.f;
    for (int k = 0; k < 256; ++k) {
      const float x = sl[t * 256 + k];
      s += x;
      ss += x * x;
    }
    const float m = s * (1.f / 256.f);
    mstat[t] = m;
    rstat[t] = rsqrtf(ss * (1.f / 256.f) - m * m + 1e-5f);
  }
  __syncthreads();
  const float w = lnw[t], bb = lnb[t];
#pragma unroll
  for (int i = 0; i < 8; ++i)
    sl[i * 256 + t] = (sl[i * 256 + t] - mstat[i]) * rstat[i] * w + bb;
  __syncthreads();
  float acc[8] = {};
  const uint4* mrow = (const uint4*)(MTB + ((long)(h * 256 + t)) * 256);
#pragma unroll 4
  for (int D8 = 0; D8 < 32; ++D8) {
    const uint4 m = mrow[D8];
#pragma unroll
    for (int i = 0; i < 8; ++i) acc[i] += dot8(m, sl + i * 256 + D8 * 8);
  }
#pragma unroll
  for (int i = 0; i < 8; ++i) {
    const int ih = i * 4 + h;
    *(unsigned short*)((char*)qt + b * 16384 + ih * 512 +
                       ((2 * t) ^ ((ih & 7) << 4))) = f2bf(acc[i]);
  }
}

// ---------------------------------------------------------------------------
// Barrier-free attention core (unchanged). Grid (8 jt, 64 b).
template <bool LAST>
__global__ __launch_bounds__(256) void k_att(
    const unsigned short* __restrict__ qt, const unsigned short* __restrict__ Xh,
    const unsigned short* __restrict__ XhT, float* __restrict__ upart,
    float* __restrict__ rowsum_part, float* __restrict__ attn_out) {
  __shared__ __align__(16) unsigned short Qs[32 * 256];
  __shared__ __align__(16) unsigned short Ps[4][1024];
  __shared__ float ured[4][2048];
  __shared__ float wred[4][32];
  const int t = threadIdx.x;
  const int lane = t & 63, wid = t >> 6;
  const int li = lane & 15, kg = lane >> 4;
  const int b = blockIdx.y;
  const long j0 = (long)blockIdx.x * 512 + wid * 128;

#pragma unroll
  for (int rnd = 0; rnd < 4; ++rnd)
    __builtin_amdgcn_global_load_lds(
        (const unsigned int*)((const char*)qt + b * 16384 + rnd * 4096 + t * 16),
        (unsigned int*)((char*)Qs + rnd * 4096 + t * 16), 16, 0, 0);
  __syncthreads();

  float rsum0 = 0.f, rsum1 = 0.f;
  f32x4 pv[2][16];
#pragma unroll
  for (int s = 0; s < 2; ++s)
#pragma unroll
    for (int ft = 0; ft < 16; ++ft) pv[s][ft] = (f32x4){0.f, 0.f, 0.f, 0.f};

  unsigned short* Pw = Ps[wid];

  for (int ch = 0; ch < 4; ++ch) {
    const long jc = j0 + ch * 32;
    f32x4 dacc[2][2];
    dacc[0][0] = (f32x4){0.f, 0.f, 0.f, 0.f};
    dacc[0][1] = (f32x4){0.f, 0.f, 0.f, 0.f};
    dacc[1][0] = (f32x4){0.f, 0.f, 0.f, 0.f};
    dacc[1][1] = (f32x4){0.f, 0.f, 0.f, 0.f};
#pragma unroll
    for (int jsub = 0; jsub < 2; ++jsub) {
      frag_ab kf[8];
      const unsigned short* kp =
          Xh + ((long)b * 4096 + jc + jsub * 16 + li) * 256 + kg * 8;
#pragma unroll
      for (int ks = 0; ks < 8; ++ks) kf[ks] = *(const frag_ab*)(kp + ks * 32);
#pragma unroll
      for (int g = 0; g < 2; ++g) {
        const char* qrow = (const char*)Qs + (g * 16 + li) * 512;
        const int swz = (li & 7) << 4;
#pragma unroll
        for (int ks = 0; ks < 8; ++ks) {
          const frag_ab qf = *(const frag_ab*)(qrow + ((ks * 64 + kg * 16) ^ swz));
          dacc[jsub][g] = __builtin_amdgcn_mfma_f32_16x16x32_bf16(
              kf[ks], qf, dacc[jsub][g], 0, 0, 0);
        }
      }
    }
    float p[2][2][4];
#pragma unroll
    for (int jsub = 0; jsub < 2; ++jsub) {
#pragma unroll
      for (int r = 0; r < 4; ++r) {
        const float d0 = dacc[jsub][0][r];
        const float d1 = dacc[jsub][1][r];
        float mx = fmaxf(d0, d1);
        mx = fmaxf(mx, __shfl_xor(mx, 1));
        mx = fmaxf(mx, __shfl_xor(mx, 2));
        mx = fmaxf(mx, __shfl_xor(mx, 4));
        mx = fmaxf(mx, __shfl_xor(mx, 8));
        float e0 = __expf(d0 - mx), e1 = __expf(d1 - mx);
        float sm = e0 + e1;
        sm += __shfl_xor(sm, 1);
        sm += __shfl_xor(sm, 2);
        sm += __shfl_xor(sm, 4);
        sm += __shfl_xor(sm, 8);
        const float inv = 1.f / sm;
        e0 *= inv;
        e1 *= inv;
        p[jsub][0][r] = e0;
        p[jsub][1][r] = e1;
        rsum0 += e0;
        rsum1 += e1;
        if (LAST) {
          float s0 = e0 + __shfl_xor(e0, 1);
          s0 += __shfl_xor(s0, 2);
          float s1 = e1 + __shfl_xor(e1, 1);
          s1 += __shfl_xor(s1, 2);
          if ((li & 3) == 0) {
            const long jg = jc + jsub * 16 + kg * 4 + r;
            attn_out[((long)b * 8 + (li >> 2)) * 4096 + jg] = s0 * 0.25f;
            attn_out[((long)b * 8 + 4 + (li >> 2)) * 4096 + jg] = s1 * 0.25f;
          }
        }
      }
    }
    asm volatile("s_waitcnt lgkmcnt(0)" ::: "memory");
#pragma unroll
    for (int g = 0; g < 2; ++g) {
      const int ih = g * 16 + li;
      char* prow = (char*)Pw + ih * 64;
      const int swz = ((ih >> 2) & 3) << 4;
#pragma unroll
      for (int jsub = 0; jsub < 2; ++jsub)
#pragma unroll
        for (int rp = 0; rp < 2; ++rp) {
          const unsigned int pk =
              (unsigned)f2bf(p[jsub][g][2 * rp]) |
              ((unsigned)f2bf(p[jsub][g][2 * rp + 1]) << 16);
          const int jb = (jsub * 16 + kg * 4 + 2 * rp) * 2;
          *(unsigned int*)(prow + (jb ^ swz)) = pk;
        }
    }
    asm volatile("s_waitcnt lgkmcnt(0)" ::: "memory");
    const frag_ab pa0 = *(const frag_ab*)(
        (const char*)Pw + li * 64 + ((kg * 16) ^ (((li >> 2) & 3) << 4)));
    const frag_ab pa1 = *(const frag_ab*)(
        (const char*)Pw + (16 + li) * 64 +
        ((kg * 16) ^ ((((16 + li) >> 2) & 3) << 4)));
#pragma unroll
    for (int ft = 0; ft < 16; ++ft) {
      const frag_ab vf = *(const frag_ab*)(
          XhT + ((long)b * 256 + ft * 16 + li) * 4096 + jc + kg * 8);
      pv[0][ft] = __builtin_amdgcn_mfma_f32_16x16x32_bf16(pa0, vf, pv[0][ft], 0, 0, 0);
      pv[1][ft] = __builtin_amdgcn_mfma_f32_16x16x32_bf16(pa1, vf, pv[1][ft], 0, 0, 0);
    }
  }

  rsum0 += __shfl_xor(rsum0, 16);
  rsum0 += __shfl_xor(rsum0, 32);
  rsum1 += __shfl_xor(rsum1, 16);
  rsum1 += __shfl_xor(rsum1, 32);
  if (lane < 16) {
    wred[wid][lane] = rsum0;
    wred[wid][16 + lane] = rsum1;
  }

  const long pb = (long)blockIdx.x * 64 + b;
#pragma unroll
  for (int p4 = 0; p4 < 4; ++p4) {
    __syncthreads();
    if ((kg >> 1) == (p4 & 1)) {
#pragma unroll
      for (int ft = 0; ft < 16; ++ft)
#pragma unroll
        for (int r = 0; r < 4; ++r)
          ured[wid][((kg & 1) * 4 + r) * 256 + ft * 16 + li] = pv[p4 >> 1][ft][r];
    }
    __syncthreads();
#pragma unroll
    for (int o = 0; o < 8; ++o) {
      const int idx = o * 256 + t;
      upart[(pb * 32 + p4 * 8 + o) * 256 + t] =
          ured[0][idx] + ured[1][idx] + ured[2][idx] + ured[3][idx];
    }
  }
  if (t < 32)
    rowsum_part[pb * 32 + t] = wred[0][t] + wred[1][t] + wred[2][t] + wred[3][t];
}

// ---------------------------------------------------------------------------
// Per-(b,i) tail with fused U-reduce: xu -> Wv -> gates -> combine -> LN -> q~.
// Grid (8 i, 64 b), 512 threads, 2 blocks/CU. bf16 weights, fp32 accum.
template <bool LAST>
__global__ __launch_bounds__(512, 4) void k_gq(
    const float* __restrict__ upart, const float* __restrict__ svx,
    const float* __restrict__ rowsum_part, const unsigned short* __restrict__ wvB,
    const unsigned short* __restrict__ wihB, const unsigned short* __restrict__ whhB,
    const float* __restrict__ bih, const float* __restrict__ bhh,
    const float* __restrict__ lnw, const float* __restrict__ lnb,
    const unsigned short* __restrict__ MTB, float* __restrict__ slots,
    unsigned short* __restrict__ qt, float* __restrict__ dout) {
  __shared__ float xul[4][256];   // xu rows h = 0..3; xul[0] reused for hn
  __shared__ float hl[256];
  __shared__ float up2[2][256];
  __shared__ float updF[256];
  __shared__ float gI[3][256], gH[3][256];
  __shared__ float snl[256];
  __shared__ float mr[2];
  const int t = threadIdx.x;
  const int i = blockIdx.x;
  const int b = blockIdx.y;
  const int f = t & 255, half = t >> 8;

  if (t < 256) hl[t] = slots[b * 2048 + i * 256 + t];
  // fused U-reduce + EPS renorm for this block's 4 xu rows
  const float svf = svx[b * 256 + f] * 1e-8f;
#pragma unroll
  for (int hh = 0; hh < 2; ++hh) {
    const int row = half * 2 + hh;
    const int ih = i * 4 + row;
    float s2 = 0.f;
#pragma unroll
    for (int p = 0; p < 8; ++p)
      s2 += rowsum_part[((long)(p * 64 + b)) * 32 + ih];
    const float rs = 1.f / (s2 + 4096.f * 1e-8f);
    float pp = 0.f;
#pragma unroll
    for (int p = 0; p < 8; ++p)
      pp += upart[(((long)(p * 64 + b)) * 32 + ih) * 256 + f];
    xul[row][f] = (pp + svf) * rs;
  }
  __syncthreads();
  // Wv: updates[gd] = sum_f wv[gd][f] * xul[gd>>6][f], split over 2 halves
  {
    const float* xr = xul[f >> 6];
    const uint4* wr = (const uint4*)(wvB + (long)f * 256 + half * 128);
    float a = 0.f;
#pragma unroll 4
    for (int k8 = 0; k8 < 16; ++k8) a += dot8(wr[k8], xr + half * 128 + k8 * 8);
    up2[half][f] = a;
  }
  __syncthreads();
  if (t < 256) updF[t] = up2[0][t] + up2[1][t];
  __syncthreads();
  // gates: col t for all; col 512+t for t<256
  {
    const int c = t;
    const uint4* wi = (const uint4*)(wihB + (long)c * 256);
    const uint4* wh = (const uint4*)(whhB + (long)c * 256);
    float gi = 0.f, gh = 0.f;
#pragma unroll 4
    for (int k8 = 0; k8 < 32; ++k8) {
      gi += dot8(wi[k8], updF + k8 * 8);
      gh += dot8(wh[k8], hl + k8 * 8);
    }
    gI[c >> 8][c & 255] = gi + bih[c];
    gH[c >> 8][c & 255] = gh + bhh[c];
  }
  if (t < 256) {
    const int c = 512 + t;
    const uint4* wi = (const uint4*)(wihB + (long)c * 256);
    const uint4* wh = (const uint4*)(whhB + (long)c * 256);
    float gi = 0.f, gh = 0.f;
#pragma unroll 4
    for (int k8 = 0; k8 < 32; ++k8) {
      gi += dot8(wi[k8], updF + k8 * 8);
      gh += dot8(wh[k8], hl + k8 * 8);
    }
    gI[2][t] = gi + bih[c];
    gH[2][t] = gh + bhh[c];
  }
  __syncthreads();
  // combine
  if (t < 256) {
    const float r = 1.f / (1.f + __expf(-(gI[0][t] + gH[0][t])));
    const float z = 1.f / (1.f + __expf(-(gI[1][t] + gH[1][t])));
    const float n = fast_tanh(gI[2][t] + r * gH[2][t]);
    const float hn = (1.f - z) * n + z * hl[t];
    slots[b * 2048 + i * 256 + t] = hn;
    if (LAST) dout[b * 2048 + i * 256 + t] = hn;
    xul[0][t] = hn;   // sn
  }
  if (LAST) return;
  __syncthreads();
  // block-local LN over xul[0]
  if (t < 64) {
    float s = 0.f, ss = 0.f;
#pragma unroll
    for (int u = 0; u < 4; ++u) {
      const float x = xul[0][u * 64 + t];
      s += x;
      ss += x * x;
    }
#pragma unroll
    for (int m = 1; m < 64; m <<= 1) {
      s += __shfl_xor(s, m);
      ss += __shfl_xor(ss, m);
    }
    if (t == 0) {
      const float mn = s * (1.f / 256.f);
      mr[0] = mn;
      mr[1] = rsqrtf(ss * (1.f / 256.f) - mn * mn + 1e-5f);
    }
  }
  __syncthreads();
  if (t < 256) snl[t] = (xul[0][t] - mr[0]) * mr[1] * lnw[t] + lnb[t];
  __syncthreads();
  // q~: thread handles (h = half*2 + hh, f): sum over 256 D via MTB rows
#pragma unroll
  for (int hh = 0; hh < 2; ++hh) {
    const int h = half * 2 + hh;
    const uint4* m = (const uint4*)(MTB + ((long)(h * 256 + f)) * 256);
    float acc = 0.f;
#pragma unroll 4
    for (int D8 = 0; D8 < 32; ++D8) acc += dot8(m[D8], snl + D8 * 8);
    const int ih = i * 4 + h;
    *(unsigned short*)((char*)qt + b * 16384 + ih * 512 +
                       ((2 * f) ^ ((ih & 7) << 4))) = f2bf(acc);
  }
}

// ---------------------------------------------------------------------------
extern "C" void kernel_launch(void* const* d_in, const int* in_sizes, int n_in,
                              void* d_out, int out_size, void* d_ws,
                              size_t ws_size, hipStream_t stream) {
  const float* xin = (const float*)d_in[0];
  const float* cond = (const float*)d_in[1];
  const float* lnin_w = (const float*)d_in[2];
  const float* lnin_b = (const float*)d_in[3];
  const float* lns_w = (const float*)d_in[4];
  const float* lns_b = (const float*)d_in[5];
  const float* wq = (const float*)d_in[6];
  const float* wk = (const float*)d_in[7];
  const float* wv = (const float*)d_in[8];
  const float* gwih = (const float*)d_in[9];
  const float* gwhh = (const float*)d_in[10];
  const float* gbih = (const float*)d_in[11];
  const float* gbhh = (const float*)d_in[12];
  float* out = (float*)d_out;

  char* ws = (char*)d_ws;
  unsigned short* Xh = (unsigned short*)ws;   ws += 262144l * 256 * 2;      // 128MB
  unsigned short* XhT = (unsigned short*)ws;  ws += 64l * 256 * 4096 * 2;   // 128MB
  unsigned short* MTB = (unsigned short*)ws;  ws += 4l * 256 * 256 * 2;
  unsigned short* qt = (unsigned short*)ws;   ws += 64l * 32 * 256 * 2;
  float* upart = (float*)ws;                  ws += 8l * 64 * 32 * 256 * 4; // 16MB
  float* svp = (float*)ws;                    ws += 4096l * 256 * 4;        // 4MB
  float* svx = (float*)ws;                    ws += 64l * 256 * 4;
  float* rowsum_part = (float*)ws;            ws += 8l * 64 * 32 * 4;
  float* slots = (float*)ws;                  ws += 512l * 256 * 4;
  unsigned short* wihB = (unsigned short*)ws; ws += 768l * 256 * 2;
  unsigned short* whhB = (unsigned short*)ws; ws += 768l * 256 * 2;
  unsigned short* wvB = (unsigned short*)ws;  ws += 256l * 256 * 2;
  // total ~281 MB

  hipMemcpyAsync(slots, cond, 512 * 256 * 4, hipMemcpyDeviceToDevice, stream);
  k_wcvt2<<<448, 256, 0, stream>>>(gwih, gwhh, wv, wihB, whhB, wvB);
  k_mprep<<<dim3(256, 4), 256, 0, stream>>>(wq, wk, MTB);
  k_precvt<<<4096, 256, 0, stream>>>(xin, lnin_w, lnin_b, Xh, XhT, svp);
  k_svr<<<64, 256, 0, stream>>>(svp, svx);
  k_q<<<dim3(64, 4), 256, 0, stream>>>(slots, lns_w, lns_b, MTB, qt);

  // iter 0
  k_att<false><<<dim3(8, 64), 256, 0, stream>>>(qt, Xh, XhT, upart,
                                                rowsum_part, out + 131072);
  k_gq<false><<<dim3(8, 64), 512, 0, stream>>>(upart, svx, rowsum_part, wvB,
                                               wihB, whhB, gbih, gbhh, lns_w,
                                               lns_b, MTB, slots, qt, out);
  // iter 1
  k_att<false><<<dim3(8, 64), 256, 0, stream>>>(qt, Xh, XhT, upart,
                                                rowsum_part, out + 131072);
  k_gq<false><<<dim3(8, 64), 512, 0, stream>>>(upart, svx, rowsum_part, wvB,
                                               wihB, whhB, gbih, gbhh, lns_w,
                                               lns_b, MTB, slots, qt, out);
  // iter 2
  k_att<true><<<dim3(8, 64), 256, 0, stream>>>(qt, Xh, XhT, upart,
                                               rowsum_part, out + 131072);
  k_gq<true><<<dim3(8, 64), 512, 0, stream>>>(upart, svx, rowsum_part, wvB,
                                              wihB, whhB, gbih, gbhh, lns_w,
                                              lns_b, MTB, slots, qt, out);
}